// Round 8
// baseline (261.832 us; speedup 1.0000x reference)
//
#include <hip/hip_runtime.h>
#include <hip/hip_bf16.h>
#include <math.h>

#define BB    1024
#define FIN   128
#define NOUT  10000
#define NBLK  79          // 128-col strips
#define NK    16
#define NPART (NBLK * 4)  // per (strip, wn, ch) partials
#define LDX   136         // LDS stride (shorts) for the X tile

typedef __attribute__((ext_vector_type(8))) short short8;
typedef __attribute__((ext_vector_type(4))) float floatx4;

__device__ __forceinline__ unsigned packbf(float a, float b) {
    __hip_bfloat162 h = __float22bfloat162_rn(make_float2(a, b));
    union { __hip_bfloat162 h2; unsigned u; } v;
    v.h2 = h;
    return v.u;
}

// ---------------------------------------------------------------------------
// Kernel A (fallback path only): per-row input inverse-norm + margin params
__global__ void rowprep(const float* __restrict__ X, const float* __restrict__ factor,
                        float* __restrict__ xinv, float* __restrict__ fa_out,
                        float* __restrict__ thr_out) {
    int b = blockIdx.x;
    int lane = threadIdx.x;
    float v0 = X[b * FIN + lane];
    float v1 = X[b * FIN + 64 + lane];
    float s = v0 * v0 + v1 * v1;
    #pragma unroll
    for (int off = 32; off > 0; off >>= 1) s += __shfl_down(s, off);
    if (lane == 0) {
        float n = sqrtf(s);
        xinv[b] = 1.0f / fmaxf(n, 1e-12f);
        float fa = powf(1.5f, factor[b] * (1.0f / 12.0f)) * 0.5f;
        fa_out[b] = fa;
        thr_out[b] = (float)M_PI - fa;
    }
}

// ---------------------------------------------------------------------------
// Kernel W: one-time W conversion + rowprep (extra 16 blocks).
// Wbf layout (same as round 7): [ch][k][strip][idx64][256B column]; col o:
//   strip=o>>7, g=o&127, ch=(g>>5)&1, idx64=((g>>6)<<5)|(g&31); within a
//   column, true chunk tc lives at byte offset ((tc ^ (o&15)) * 16).
// NEW: packed output staged in LDS (wout), then streamed out coalesced
// (two contiguous 16 KB regions) — kills the 256B-stride 16B write scatter.
__global__ __launch_bounds__(256) void wconv(
    const float* __restrict__ W, unsigned char* __restrict__ Wbf,
    const float* __restrict__ X, const float* __restrict__ factor,
    float* __restrict__ xinv, float* __restrict__ fa_out, float* __restrict__ thr_out) {

    __shared__ float xs2[128 * 128];   // [f][o] fp32 (64 KB)
    __shared__ uint4 wout[2048];       // packed output (32 KB)
    __shared__ float sq2[256];
    __shared__ float wis[128];

    const int tid = threadIdx.x;

    // ---- rowprep blocks ----
    if (blockIdx.x >= NK * NBLK) {
        int rb = blockIdx.x - NK * NBLK;   // 0..15
        int w4 = tid >> 6, lane = tid & 63;
        for (int i = w4; i < 64; i += 4) {
            int row = rb * 64 + i;
            float v0 = X[row * FIN + lane];
            float v1 = X[row * FIN + 64 + lane];
            float s = v0 * v0 + v1 * v1;
            #pragma unroll
            for (int off = 32; off > 0; off >>= 1) s += __shfl_down(s, off);
            if (lane == 0) {
                xinv[row] = 1.0f / fmaxf(sqrtf(s), 1e-12f);
                float fa = powf(1.5f, factor[row] * (1.0f / 12.0f)) * 0.5f;
                fa_out[row] = fa;
                thr_out[row] = (float)M_PI - fa;
            }
        }
        return;
    }

    const int k = blockIdx.x / NBLK;
    const int strip = blockIdx.x - k * NBLK;
    const int o0 = strip * 128;

    // stage 128f x 128o = 4096 float4; 256 threads -> 16 iters
    #pragma unroll
    for (int it = 0; it < 16; it++) {
        int idx = it * 256 + tid;
        int f = idx >> 5;
        int c4 = idx & 31;
        int o = o0 + c4 * 4;
        float4 v = make_float4(0.f, 0.f, 0.f, 0.f);
        if (o < NOUT)
            v = *(const float4*)(W + ((size_t)k * FIN + f) * NOUT + o);
        *(float4*)(xs2 + f * 128 + c4 * 4) = v;
    }
    __syncthreads();

    const int col = tid & 127;
    const int half = tid >> 7;
    float s = 0.0f;
    #pragma unroll 8
    for (int f2 = 0; f2 < 64; f2++) {
        float x = xs2[(half * 64 + f2) * 128 + col];
        s = fmaf(x, x, s);
    }
    sq2[half * 128 + col] = s;
    __syncthreads();
    if (tid < 128)
        wis[tid] = 1.0f / fmaxf(sqrtf(sq2[tid] + sq2[tid + 128]), 1e-12f);
    __syncthreads();

    const float wi = wis[col];
    const int ch = (col >> 5) & 1;
    const int idx64 = ((col >> 6) << 5) | (col & 31);
    #pragma unroll
    for (int tcl = 0; tcl < 8; tcl++) {
        int tc = half * 8 + tcl;
        float v0 = xs2[(tc * 8 + 0) * 128 + col] * wi;
        float v1 = xs2[(tc * 8 + 1) * 128 + col] * wi;
        float v2 = xs2[(tc * 8 + 2) * 128 + col] * wi;
        float v3 = xs2[(tc * 8 + 3) * 128 + col] * wi;
        float v4 = xs2[(tc * 8 + 4) * 128 + col] * wi;
        float v5 = xs2[(tc * 8 + 5) * 128 + col] * wi;
        float v6 = xs2[(tc * 8 + 6) * 128 + col] * wi;
        float v7 = xs2[(tc * 8 + 7) * 128 + col] * wi;
        uint4 u;
        u.x = packbf(v0, v1);
        u.y = packbf(v2, v3);
        u.z = packbf(v4, v5);
        u.w = packbf(v6, v7);
        wout[ch * 1024 + idx64 * 16 + (tc ^ (col & 15))] = u;
    }
    __syncthreads();

    // coalesced copy-out: two contiguous 16 KB regions
    #pragma unroll
    for (int c = 0; c < 2; c++) {
        unsigned char* dst = Wbf + (((size_t)(c * NK + k)) * NBLK + strip) * 16384;
        #pragma unroll
        for (int i = 0; i < 4; i++) {
            int idx = i * 256 + tid;
            *(uint4*)(dst + (size_t)idx * 16) = wout[c * 1024 + idx];
        }
    }
}

// ---------------------------------------------------------------------------
// Kernel B: MFMA GEMM + max-over-k + partial online-softmax.
// NO barriers in the k-loop: B streams global->registers per wave (each wave
// owns a 32-column slice; swizzled layout keeps each q-quad inside one
// aligned 64B line -> coalesced). Register double-buffer bA/bB, k unrolled
// x2. A frags (X*xinv, bf16) k-invariant in registers; LDS only for X stage.
__global__ __launch_bounds__(256, 2) void gemm_mx(
    const float* __restrict__ X, const unsigned char* __restrict__ Wbf,
    const int* __restrict__ label, const float* __restrict__ xinv,
    float2* __restrict__ partial, float* __restrict__ cosl) {

    __shared__ short xs[128 * LDX];   // 34816 B

    const int tid  = threadIdx.x;
    const int lane = tid & 63;
    const int w    = tid >> 6;
    const int l15  = lane & 15;
    const int q    = lane >> 4;
    const int wm   = w & 1;
    const int wn   = w >> 1;

    // XCD-aware decode: ids {group*64 + y*8 + xcd} -> jb = group*8+xcd
    const int id    = blockIdx.x;
    const int group = id >> 6;
    const int sub   = id & 63;
    const int jb    = group * 8 + (sub & 7);
    const int y     = sub >> 3;
    if (jb >= NBLK) return;
    const int r0 = y * 128;
    const int o0 = jb * 128;

    // ---- stage X tile as bf16 with xinv folded ----
    #pragma unroll
    for (int it = 0; it < 16; it++) {
        int idx = it * 256 + tid;
        int row = idx >> 5;
        int c4  = idx & 31;
        const float4 v = *(const float4*)(X + (size_t)(r0 + row) * FIN + c4 * 4);
        float xi = xinv[r0 + row];
        uint2 p;
        p.x = packbf(v.x * xi, v.y * xi);
        p.y = packbf(v.z * xi, v.w * xi);
        *(uint2*)(xs + row * LDX + c4 * 4) = p;
    }
    __syncthreads();

    short8 af[4][4];
    #pragma unroll
    for (int mt = 0; mt < 4; mt++)
        #pragma unroll
        for (int kk = 0; kk < 4; kk++)
            af[mt][kk] = *(const short8*)(xs + (wm * 64 + mt * 16 + l15) * LDX + kk * 32 + q * 8);
    // no further LDS use; no more barriers

    const unsigned char* wb0 = Wbf + (size_t)jb * 16384 + (size_t)(wn * 32 + l15) * 256;
    const size_t ckstr = (size_t)NBLK * 16384;
    int slot[4];
    #pragma unroll
    for (int kk = 0; kk < 4; kk++) slot[kk] = (((kk * 4 + q) ^ l15) * 16);

    auto loadck = [&](int ck, short8* dst) {
        const unsigned char* p = wb0 + (size_t)ck * ckstr;
        #pragma unroll
        for (int n2 = 0; n2 < 2; n2++)
            #pragma unroll
            for (int kk = 0; kk < 4; kk++)
                dst[n2 * 4 + kk] = *(const short8*)(p + n2 * 4096 + slot[kk]);
    };

    short8 bA[8], bB[8];
    loadck(0, bA);

    for (int ch = 0; ch < 2; ch++) {
        floatx4 maxv[4][2];
        #pragma unroll
        for (int mt = 0; mt < 4; mt++)
            #pragma unroll
            for (int n2 = 0; n2 < 2; n2++)
                #pragma unroll
                for (int r = 0; r < 4; r++)
                    maxv[mt][n2][r] = -INFINITY;

        for (int k = 0; k < NK; k += 2) {
            const int ck = ch * NK + k;
            loadck(ck + 1, bB);
            #pragma unroll
            for (int n2 = 0; n2 < 2; n2++) {
                floatx4 acc[4];
                #pragma unroll
                for (int mt = 0; mt < 4; mt++) acc[mt] = (floatx4){0.f, 0.f, 0.f, 0.f};
                #pragma unroll
                for (int kk = 0; kk < 4; kk++)
                    #pragma unroll
                    for (int mt = 0; mt < 4; mt++)
                        acc[mt] = __builtin_amdgcn_mfma_f32_16x16x32_bf16(af[mt][kk], bA[n2 * 4 + kk], acc[mt], 0, 0, 0);
                #pragma unroll
                for (int mt = 0; mt < 4; mt++)
                    #pragma unroll
                    for (int r = 0; r < 4; r++)
                        maxv[mt][n2][r] = fmaxf(maxv[mt][n2][r], acc[mt][r]);
            }
            if (ck + 2 < 2 * NK) loadck(ck + 2, bA);
            #pragma unroll
            for (int n2 = 0; n2 < 2; n2++) {
                floatx4 acc[4];
                #pragma unroll
                for (int mt = 0; mt < 4; mt++) acc[mt] = (floatx4){0.f, 0.f, 0.f, 0.f};
                #pragma unroll
                for (int kk = 0; kk < 4; kk++)
                    #pragma unroll
                    for (int mt = 0; mt < 4; mt++)
                        acc[mt] = __builtin_amdgcn_mfma_f32_16x16x32_bf16(af[mt][kk], bB[n2 * 4 + kk], acc[mt], 0, 0, 0);
                #pragma unroll
                for (int mt = 0; mt < 4; mt++)
                    #pragma unroll
                    for (int r = 0; r < 4; r++)
                        maxv[mt][n2][r] = fmaxf(maxv[mt][n2][r], acc[mt][r]);
            }
        }

        // ---- per-ch epilogue: partial online-softmax (label col excluded) ----
        #pragma unroll
        for (int mt = 0; mt < 4; mt++) {
            #pragma unroll
            for (int rr = 0; rr < 4; rr++) {
                int row = r0 + wm * 64 + mt * 16 + q * 4 + rr;
                int lb = label[row];
                float m = -1e30f, s = 0.f;
                #pragma unroll
                for (int n2 = 0; n2 < 2; n2++) {
                    int o = o0 + wn * 64 + ch * 32 + n2 * 16 + l15;
                    if (o < NOUT) {
                        float c = maxv[mt][n2][rr];
                        if (o == lb) {
                            cosl[row] = c;   // unique writer grid-wide
                        } else {
                            float l = 64.0f * fminf(fmaxf(c, -1.0f + 1e-6f), 1.0f - 1e-6f);
                            if (l > m) { s = s * __expf(m - l) + 1.0f; m = l; }
                            else       { s += __expf(l - m); }
                        }
                    }
                }
                #pragma unroll
                for (int off = 1; off <= 8; off <<= 1) {
                    float m2 = __shfl_xor(m, off);
                    float s2 = __shfl_xor(s, off);
                    float M = fmaxf(m, m2);
                    s = s * __expf(m - M) + s2 * __expf(m2 - M);
                    m = M;
                }
                if (l15 == 0)
                    partial[(size_t)row * NPART + jb * 4 + wn * 2 + ch] = make_float2(m, s);
            }
        }
    }
}

// ---------------------------------------------------------------------------
// Fallback GEMM (round-3 path) used when ws_size can't hold Wbf.
__global__ __launch_bounds__(256, 2) void gemm_stats(
    const float* __restrict__ X, const float* __restrict__ W,
    const int* __restrict__ label, const float* __restrict__ xinv,
    float2* __restrict__ partial, float* __restrict__ cosl) {

    __shared__ short xs[128 * LDX];
    __shared__ short wt[128 * LDX];
    __shared__ float sqs[128][2];

    const int tid  = threadIdx.x;
    const int lane = tid & 63;
    const int w    = tid >> 6;
    const int l15  = lane & 15;
    const int q    = lane >> 4;
    const int wm   = w & 1;
    const int wn   = w >> 1;

    const int id    = blockIdx.x;
    const int group = id >> 6;
    const int sub   = id & 63;
    const int jb    = group * 8 + (sub & 7);
    const int y     = sub >> 3;
    if (jb >= NBLK) return;
    const int r0 = y * 128;
    const int o0 = jb * 128;

    #pragma unroll
    for (int it = 0; it < 16; it++) {
        int idx = it * 256 + tid;
        int row = idx >> 5;
        int c4  = idx & 31;
        const float4 v = *(const float4*)(X + (size_t)(r0 + row) * FIN + c4 * 4);
        uint2 p;
        p.x = packbf(v.x, v.y);
        p.y = packbf(v.z, v.w);
        *(uint2*)(xs + row * LDX + c4 * 4) = p;
    }

    const int st_o = (w & 1) * 64 + lane;
    const int st_f = (w >> 1) * 64;
    const int st_h = w >> 1;
    const int go   = o0 + st_o;
    const bool ov  = go < NOUT;

    float rw[64];
    {
        const float* Wp = W + (size_t)st_f * NOUT + go;
        #pragma unroll
        for (int g = 0; g < 16; g++)
            #pragma unroll
            for (int c = 0; c < 4; c++)
                rw[g * 4 + c] = ov ? Wp[(size_t)(g * 4 + c) * NOUT] : 0.0f;
    }
    __syncthreads();

    short8 af[4][4];
    #pragma unroll
    for (int mt = 0; mt < 4; mt++)
        #pragma unroll
        for (int kk = 0; kk < 4; kk++)
            af[mt][kk] = *(const short8*)(xs + (wm * 64 + mt * 16 + l15) * LDX + kk * 32 + q * 8);

    floatx4 maxv[4][4];
    #pragma unroll
    for (int mt = 0; mt < 4; mt++)
        #pragma unroll
        for (int nt = 0; nt < 4; nt++)
            #pragma unroll
            for (int r = 0; r < 4; r++)
                maxv[mt][nt][r] = -INFINITY;

    for (int k = 0; k < NK; k++) {
        float sq = 0.0f;
        uint2 pk[16];
        #pragma unroll
        for (int g = 0; g < 16; g++) {
            float a0 = rw[g * 4 + 0], a1 = rw[g * 4 + 1];
            float a2 = rw[g * 4 + 2], a3 = rw[g * 4 + 3];
            sq = fmaf(a0, a0, sq); sq = fmaf(a1, a1, sq);
            sq = fmaf(a2, a2, sq); sq = fmaf(a3, a3, sq);
            pk[g].x = packbf(a0, a1);
            pk[g].y = packbf(a2, a3);
        }
        __syncthreads();
        #pragma unroll
        for (int g = 0; g < 16; g++)
            *(uint2*)(wt + st_o * LDX + st_f + g * 4) = pk[g];
        sqs[st_o][st_h] = sq;
        __syncthreads();

        if (k < NK - 1) {
            const float* Wn = W + ((size_t)(k + 1) * FIN + st_f) * NOUT + go;
            #pragma unroll
            for (int g = 0; g < 16; g++)
                #pragma unroll
                for (int c = 0; c < 4; c++)
                    rw[g * 4 + c] = ov ? Wn[(size_t)(g * 4 + c) * NOUT] : 0.0f;
        }

        float wv[4];
        #pragma unroll
        for (int nt = 0; nt < 4; nt++) {
            int col = wn * 64 + nt * 16 + l15;
            wv[nt] = 1.0f / fmaxf(sqrtf(sqs[col][0] + sqs[col][1]), 1e-12f);
        }

        #pragma unroll
        for (int h = 0; h < 2; h++) {
            floatx4 acc[4][2];
            #pragma unroll
            for (int mt = 0; mt < 4; mt++) {
                acc[mt][0] = (floatx4){0.f, 0.f, 0.f, 0.f};
                acc[mt][1] = (floatx4){0.f, 0.f, 0.f, 0.f};
            }
            #pragma unroll
            for (int kk = 0; kk < 4; kk++) {
                short8 bf0 = *(const short8*)(wt + (wn * 64 + (h * 2 + 0) * 16 + l15) * LDX + kk * 32 + q * 8);
                short8 bf1 = *(const short8*)(wt + (wn * 64 + (h * 2 + 1) * 16 + l15) * LDX + kk * 32 + q * 8);
                #pragma unroll
                for (int mt = 0; mt < 4; mt++) {
                    acc[mt][0] = __builtin_amdgcn_mfma_f32_16x16x32_bf16(af[mt][kk], bf0, acc[mt][0], 0, 0, 0);
                    acc[mt][1] = __builtin_amdgcn_mfma_f32_16x16x32_bf16(af[mt][kk], bf1, acc[mt][1], 0, 0, 0);
                }
            }
            #pragma unroll
            for (int mt = 0; mt < 4; mt++)
                #pragma unroll
                for (int n2 = 0; n2 < 2; n2++)
                    #pragma unroll
                    for (int r = 0; r < 4; r++)
                        maxv[mt][h * 2 + n2][r] =
                            fmaxf(maxv[mt][h * 2 + n2][r], acc[mt][n2][r] * wv[h * 2 + n2]);
        }
    }

    #pragma unroll
    for (int mt = 0; mt < 4; mt++) {
        #pragma unroll
        for (int rr = 0; rr < 4; rr++) {
            int row = r0 + wm * 64 + mt * 16 + q * 4 + rr;
            float xi = xinv[row];
            int lb = label[row];
            float m = -1e30f, s = 0.f;
            #pragma unroll
            for (int nt = 0; nt < 4; nt++) {
                int o = o0 + wn * 64 + nt * 16 + l15;
                if (o < NOUT) {
                    float c = maxv[mt][nt][rr] * xi;
                    if (o == lb) {
                        cosl[row] = c;
                    } else {
                        float l = 64.0f * fminf(fmaxf(c, -1.0f + 1e-6f), 1.0f - 1e-6f);
                        if (l > m) { s = s * __expf(m - l) + 1.0f; m = l; }
                        else       { s += __expf(l - m); }
                    }
                }
            }
            #pragma unroll
            for (int off = 1; off <= 8; off <<= 1) {
                float m2 = __shfl_xor(m, off);
                float s2 = __shfl_xor(s, off);
                float M = fmaxf(m, m2);
                s = s * __expf(m - M) + s2 * __expf(m2 - M);
                m = M;
            }
            if (l15 == 0) {
                partial[(size_t)row * NPART + jb * 4 + wn * 2 + 0] = make_float2(m, s);
                partial[(size_t)row * NPART + jb * 4 + wn * 2 + 1] = make_float2(-1e30f, 0.f);
            }
        }
    }
}

// ---------------------------------------------------------------------------
// Kernel C1: per-row combine + margin -> (loss, corr) per row. No atomics.
__global__ void finalize_rows(const float2* __restrict__ partial, const float* __restrict__ cosl,
                              const float* __restrict__ fa, const float* __restrict__ thr,
                              float2* __restrict__ rowres) {
    int w = threadIdx.x >> 6;
    int lane = threadIdx.x & 63;
    int b = blockIdx.x * 4 + w;
    float m = -1e30f, s = 0.0f;
    for (int j = lane; j < NPART; j += 64) {
        float2 p = partial[(size_t)b * NPART + j];
        float M = fmaxf(m, p.x);
        s = s * __expf(m - M) + p.y * __expf(p.x - M);
        m = M;
    }
    #pragma unroll
    for (int off = 1; off < 64; off <<= 1) {
        float m2 = __shfl_xor(m, off);
        float s2 = __shfl_xor(s, off);
        float M = fmaxf(m, m2);
        s = s * __expf(m - M) + s2 * __expf(m2 - M);
        m = M;
    }
    if (lane == 0) {
        float c = fminf(fmaxf(cosl[b], -1.0f + 1e-6f), 1.0f - 1e-6f);
        float theta = acosf(c);
        float ll = (theta > thr[b]) ? 64.0f * c : 64.0f * cosf(theta + fa[b]);
        float M = fmaxf(m, ll);
        float S = s * __expf(m - M) + __expf(ll - M);
        rowres[b] = make_float2(M + logf(S) - ll, (ll > m) ? 100.0f : 0.0f);
    }
}

// Kernel C2: deterministic tree reduce of 1024 rows -> 2 scalars.
__global__ void finalize_sum(const float2* __restrict__ rowres, float* __restrict__ out) {
    __shared__ float sl[1024];
    __shared__ float sc[1024];
    int b = threadIdx.x;
    float2 v = rowres[b];
    sl[b] = v.x;
    sc[b] = v.y;
    __syncthreads();
    for (int st = 512; st > 0; st >>= 1) {
        if (b < st) { sl[b] += sl[b + st]; sc[b] += sc[b + st]; }
        __syncthreads();
    }
    if (b == 0) {
        out[0] = sl[0] * (1.0f / 1024.0f);
        out[1] = sc[0] * (1.0f / 1024.0f);
    }
}

// ---------------------------------------------------------------------------
extern "C" void kernel_launch(void* const* d_in, const int* in_sizes, int n_in,
                              void* d_out, int out_size, void* d_ws, size_t ws_size,
                              hipStream_t stream) {
    const float* X      = (const float*)d_in[0];
    const float* factor = (const float*)d_in[1];
    const int*   label  = (const int*)d_in[2];
    const float* W      = (const float*)d_in[3];
    float* out = (float*)d_out;
    float* ws  = (float*)d_ws;

    float*  xinv = ws;                        // 1024
    float*  fa   = ws + 1024;                 // 1024
    float*  thr  = ws + 2048;                 // 1024
    float*  cosl = ws + 3072;                 // 1024
    float2* rowres = (float2*)(ws + 4096);    // 1024 float2
    float2* partial = (float2*)(ws + 6144);   // 1024 x NPART float2 (~2.6 MB)
    unsigned char* Wbf = (unsigned char*)d_ws + 4 * 1024 * 1024;  // 41.4 MB

    const size_t wbf_bytes = (size_t)NK * 2 * NBLK * 64 * 256;
    const size_t need = 4ull * 1024 * 1024 + wbf_bytes;

    if (ws_size >= need) {
        wconv<<<NK * NBLK + 16, 256, 0, stream>>>(W, Wbf, X, factor, xinv, fa, thr);
        gemm_mx<<<640, 256, 0, stream>>>(X, Wbf, label, xinv, partial, cosl);
    } else {
        rowprep<<<BB, 64, 0, stream>>>(X, factor, xinv, fa, thr);
        gemm_stats<<<640, 256, 0, stream>>>(X, W, label, xinv, partial, cosl);
    }
    finalize_rows<<<BB / 4, 256, 0, stream>>>(partial, cosl, fa, thr, rowres);
    finalize_sum<<<1, BB, 0, stream>>>(rowres, out);
}

// Round 9
// 218.075 us; speedup vs baseline: 1.2006x; 1.2006x over previous
//
#include <hip/hip_runtime.h>
#include <hip/hip_bf16.h>
#include <math.h>

#define BB    1024
#define FIN   128
#define NOUT  10000
#define NBLK  79          // 128-col strips (fallback path)
#define NCB   158         // 64-col blocks (fast path)
#define NK    16
#define NPART (NCB * 2)   // per (cb, wn) partials == NBLK*4
#define LDX   136         // LDS stride (shorts) for the X tile

typedef __attribute__((ext_vector_type(8))) short short8;
typedef __attribute__((ext_vector_type(4))) float floatx4;

__device__ __forceinline__ unsigned packbf(float a, float b) {
    __hip_bfloat162 h = __float22bfloat162_rn(make_float2(a, b));
    union { __hip_bfloat162 h2; unsigned u; } v;
    v.h2 = h;
    return v.u;
}

// ---------------------------------------------------------------------------
// Kernel A (fallback path only): per-row input inverse-norm + margin params
__global__ void rowprep(const float* __restrict__ X, const float* __restrict__ factor,
                        float* __restrict__ xinv, float* __restrict__ fa_out,
                        float* __restrict__ thr_out) {
    int b = blockIdx.x;
    int lane = threadIdx.x;
    float v0 = X[b * FIN + lane];
    float v1 = X[b * FIN + 64 + lane];
    float s = v0 * v0 + v1 * v1;
    #pragma unroll
    for (int off = 32; off > 0; off >>= 1) s += __shfl_down(s, off);
    if (lane == 0) {
        float n = sqrtf(s);
        xinv[b] = 1.0f / fmaxf(n, 1e-12f);
        float fa = powf(1.5f, factor[b] * (1.0f / 12.0f)) * 0.5f;
        fa_out[b] = fa;
        thr_out[b] = (float)M_PI - fa;
    }
}

// ---------------------------------------------------------------------------
// Kernel W: one-time W conversion + rowprep (last 16 blocks).
// Wbf layout (fully linear for gemm): per (k, cb) a 16 KB region:
//   [wn(2)][n2(2)][kk(4)][lane(64)][16B],  lane = q*16 + l15,
// holding bf16( W[k][f][o] * winv[k][o] ) with
//   o = cb*64 + wn*32 + n2*16 + l15,  f = (kk*4+q)*8 .. +7.
// Each gemm B-load (fixed wn,n2,kk) reads 1 KB CONTIGUOUS.
// Block = (k, cb): LDS 32KB stage + 16KB pack + ~1.3KB -> 3 blocks/CU.
__global__ __launch_bounds__(256) void wconv(
    const float* __restrict__ W, unsigned char* __restrict__ Wbf,
    const float* __restrict__ X, const float* __restrict__ factor,
    float* __restrict__ xinv, float* __restrict__ fa_out, float* __restrict__ thr_out) {

    __shared__ float xs2[128 * 64];   // [f][c] fp32 (32 KB)
    __shared__ uint4 wout[1024];      // packed 16 KB
    __shared__ float sq2[256];
    __shared__ float wis[64];

    const int tid = threadIdx.x;

    // ---- rowprep blocks ----
    if (blockIdx.x >= NK * NCB) {
        int rb = blockIdx.x - NK * NCB;   // 0..15
        int w4 = tid >> 6, lane = tid & 63;
        for (int i = w4; i < 64; i += 4) {
            int row = rb * 64 + i;
            float v0 = X[row * FIN + lane];
            float v1 = X[row * FIN + 64 + lane];
            float s = v0 * v0 + v1 * v1;
            #pragma unroll
            for (int off = 32; off > 0; off >>= 1) s += __shfl_down(s, off);
            if (lane == 0) {
                xinv[row] = 1.0f / fmaxf(sqrtf(s), 1e-12f);
                float fa = powf(1.5f, factor[row] * (1.0f / 12.0f)) * 0.5f;
                fa_out[row] = fa;
                thr_out[row] = (float)M_PI - fa;
            }
        }
        return;
    }

    const int k  = blockIdx.x / NCB;
    const int cb = blockIdx.x - k * NCB;
    const int o0 = cb * 64;

    // stage 128f x 64o = 2048 float4; 8 iters, coalesced (zero-fill past NOUT)
    #pragma unroll
    for (int it = 0; it < 8; it++) {
        int idx = it * 256 + tid;      // float4 index 0..2047
        int f  = idx >> 4;             // 16 float4 per f-row
        int c4 = idx & 15;
        int o  = o0 + c4 * 4;
        float4 v = make_float4(0.f, 0.f, 0.f, 0.f);
        if (o < NOUT)
            v = *(const float4*)(W + ((size_t)k * FIN + f) * NOUT + o);
        *(float4*)(xs2 + f * 64 + c4 * 4) = v;
    }
    __syncthreads();

    // sumsq: 4 segments of 32 features per column
    {
        const int col = tid & 63;
        const int seg = tid >> 6;
        float s = 0.0f;
        #pragma unroll 8
        for (int f2 = 0; f2 < 32; f2++) {
            float x = xs2[(seg * 32 + f2) * 64 + col];
            s = fmaf(x, x, s);
        }
        sq2[tid] = s;
    }
    __syncthreads();
    if (tid < 64)
        wis[tid] = 1.0f / fmaxf(sqrtf(sq2[tid] + sq2[tid + 64] + sq2[tid + 128] + sq2[tid + 192]), 1e-12f);
    __syncthreads();

    // pack: thread (c = tid>>2, sub = tid&3) writes chunks tc = sub*4+i
    {
        const int c   = tid >> 2;
        const int sub = tid & 3;
        const float wi = wis[c];
        const int wn  = c >> 5;
        const int n2  = (c >> 4) & 1;
        const int l15 = c & 15;
        #pragma unroll
        for (int i = 0; i < 4; i++) {
            int tc = sub * 4 + i;          // feature chunk: f = tc*8..tc*8+7
            int kk = tc >> 2;
            int q  = tc & 3;
            float v0 = xs2[(tc * 8 + 0) * 64 + c] * wi;
            float v1 = xs2[(tc * 8 + 1) * 64 + c] * wi;
            float v2 = xs2[(tc * 8 + 2) * 64 + c] * wi;
            float v3 = xs2[(tc * 8 + 3) * 64 + c] * wi;
            float v4 = xs2[(tc * 8 + 4) * 64 + c] * wi;
            float v5 = xs2[(tc * 8 + 5) * 64 + c] * wi;
            float v6 = xs2[(tc * 8 + 6) * 64 + c] * wi;
            float v7 = xs2[(tc * 8 + 7) * 64 + c] * wi;
            uint4 u;
            u.x = packbf(v0, v1);
            u.y = packbf(v2, v3);
            u.z = packbf(v4, v5);
            u.w = packbf(v6, v7);
            wout[wn * 512 + n2 * 256 + kk * 64 + q * 16 + l15] = u;
        }
    }
    __syncthreads();

    // coalesced copy-out: one contiguous 16 KB region
    unsigned char* dst = Wbf + ((size_t)k * NCB + cb) * 16384;
    #pragma unroll
    for (int i = 0; i < 4; i++) {
        int idx = i * 256 + tid;
        *(uint4*)(dst + (size_t)idx * 16) = wout[idx];
    }
}

// ---------------------------------------------------------------------------
// Kernel B: MFMA GEMM + max-over-k + partial online-softmax.
// Block = 64 rows x 64 cols, 4 waves of 32x32 (wm,wn). Grid 2528 (+pad).
// af 32 + maxv 16 + bA/bB 64 regs -> ~135 live -> 3 waves/SIMD residency.
// B streams global->registers, 1 KB contiguous per load, no k-loop barriers.
__global__ __launch_bounds__(256, 2) void gemm_mx(
    const float* __restrict__ X, const unsigned char* __restrict__ Wbf,
    const int* __restrict__ label, const float* __restrict__ xinv,
    float2* __restrict__ partial, float* __restrict__ cosl) {

    __shared__ short xs[64 * LDX];   // 17408 B

    const int tid  = threadIdx.x;
    const int lane = tid & 63;
    const int w    = tid >> 6;
    const int l15  = lane & 15;
    const int q    = lane >> 4;
    const int wm   = w & 1;
    const int wn   = w >> 1;

    // XCD-aware decode: ids {group*128 + y*8 + xcd} -> cb = group*8 + xcd
    const int id    = blockIdx.x;
    const int group = id >> 7;
    const int sub   = id & 127;
    const int cb    = group * 8 + (sub & 7);
    const int y     = sub >> 3;            // 0..15
    if (cb >= NCB) return;
    const int r0 = y * 64;
    const int o0 = cb * 64;

    // ---- stage X tile (64 rows) as bf16 with xinv folded ----
    #pragma unroll
    for (int it = 0; it < 8; it++) {
        int idx = it * 256 + tid;      // float4 index 0..2047
        int row = idx >> 5;
        int c4  = idx & 31;
        const float4 v = *(const float4*)(X + (size_t)(r0 + row) * FIN + c4 * 4);
        float xi = xinv[r0 + row];
        uint2 p;
        p.x = packbf(v.x * xi, v.y * xi);
        p.y = packbf(v.z * xi, v.w * xi);
        *(uint2*)(xs + row * LDX + c4 * 4) = p;
    }
    __syncthreads();

    short8 af[2][4];
    #pragma unroll
    for (int mt = 0; mt < 2; mt++)
        #pragma unroll
        for (int kk = 0; kk < 4; kk++)
            af[mt][kk] = *(const short8*)(xs + (wm * 32 + mt * 16 + l15) * LDX + kk * 32 + q * 8);
    // no further LDS use; no more barriers

    const unsigned char* wbase = Wbf + (size_t)cb * 16384 + (size_t)wn * 8192 + (size_t)lane * 16;
    const size_t kstr = (size_t)NCB * 16384;

    auto loadk = [&](int k, short8* dst) {
        const unsigned char* p = wbase + (size_t)k * kstr;
        #pragma unroll
        for (int n2 = 0; n2 < 2; n2++)
            #pragma unroll
            for (int kk = 0; kk < 4; kk++)
                dst[n2 * 4 + kk] = *(const short8*)(p + n2 * 4096 + kk * 1024);
    };

    floatx4 maxv[2][2];
    #pragma unroll
    for (int mt = 0; mt < 2; mt++)
        #pragma unroll
        for (int n2 = 0; n2 < 2; n2++)
            #pragma unroll
            for (int r = 0; r < 4; r++)
                maxv[mt][n2][r] = -INFINITY;

    auto compute = [&](const short8* b) {
        floatx4 acc[2][2];
        #pragma unroll
        for (int mt = 0; mt < 2; mt++)
            #pragma unroll
            for (int n2 = 0; n2 < 2; n2++)
                acc[mt][n2] = (floatx4){0.f, 0.f, 0.f, 0.f};
        #pragma unroll
        for (int kk = 0; kk < 4; kk++)
            #pragma unroll
            for (int mt = 0; mt < 2; mt++)
                #pragma unroll
                for (int n2 = 0; n2 < 2; n2++)
                    acc[mt][n2] = __builtin_amdgcn_mfma_f32_16x16x32_bf16(
                        af[mt][kk], b[n2 * 4 + kk], acc[mt][n2], 0, 0, 0);
        #pragma unroll
        for (int mt = 0; mt < 2; mt++)
            #pragma unroll
            for (int n2 = 0; n2 < 2; n2++)
                #pragma unroll
                for (int r = 0; r < 4; r++)
                    maxv[mt][n2][r] = fmaxf(maxv[mt][n2][r], acc[mt][n2][r]);
    };

    short8 bA[8], bB[8];
    loadk(0, bA);
    for (int k = 0; k < NK; k += 2) {
        loadk(k + 1, bB);
        compute(bA);
        if (k + 2 < NK) loadk(k + 2, bA);
        compute(bB);
    }

    // ---- epilogue: per-row partial online-softmax (label col excluded) ----
    #pragma unroll
    for (int mt = 0; mt < 2; mt++) {
        #pragma unroll
        for (int rr = 0; rr < 4; rr++) {
            int row = r0 + wm * 32 + mt * 16 + q * 4 + rr;
            int lb = label[row];
            float m = -1e30f, s = 0.f;
            #pragma unroll
            for (int n2 = 0; n2 < 2; n2++) {
                int o = o0 + wn * 32 + n2 * 16 + l15;
                if (o < NOUT) {
                    float c = maxv[mt][n2][rr];
                    if (o == lb) {
                        cosl[row] = c;   // unique writer grid-wide
                    } else {
                        float l = 64.0f * fminf(fmaxf(c, -1.0f + 1e-6f), 1.0f - 1e-6f);
                        if (l > m) { s = s * __expf(m - l) + 1.0f; m = l; }
                        else       { s += __expf(l - m); }
                    }
                }
            }
            #pragma unroll
            for (int off = 1; off <= 8; off <<= 1) {
                float m2 = __shfl_xor(m, off);
                float s2 = __shfl_xor(s, off);
                float M = fmaxf(m, m2);
                s = s * __expf(m - M) + s2 * __expf(m2 - M);
                m = M;
            }
            if (l15 == 0)
                partial[(size_t)row * NPART + cb * 2 + wn] = make_float2(m, s);
        }
    }
}

// ---------------------------------------------------------------------------
// Fallback GEMM (round-3 path) used when ws_size can't hold Wbf.
__global__ __launch_bounds__(256, 2) void gemm_stats(
    const float* __restrict__ X, const float* __restrict__ W,
    const int* __restrict__ label, const float* __restrict__ xinv,
    float2* __restrict__ partial, float* __restrict__ cosl) {

    __shared__ short xs[128 * LDX];
    __shared__ short wt[128 * LDX];
    __shared__ float sqs[128][2];

    const int tid  = threadIdx.x;
    const int lane = tid & 63;
    const int w    = tid >> 6;
    const int l15  = lane & 15;
    const int q    = lane >> 4;
    const int wm   = w & 1;
    const int wn   = w >> 1;

    const int id    = blockIdx.x;
    const int group = id >> 6;
    const int sub   = id & 63;
    const int jb    = group * 8 + (sub & 7);
    const int y     = sub >> 3;
    if (jb >= NBLK) return;
    const int r0 = y * 128;
    const int o0 = jb * 128;

    #pragma unroll
    for (int it = 0; it < 16; it++) {
        int idx = it * 256 + tid;
        int row = idx >> 5;
        int c4  = idx & 31;
        const float4 v = *(const float4*)(X + (size_t)(r0 + row) * FIN + c4 * 4);
        uint2 p;
        p.x = packbf(v.x, v.y);
        p.y = packbf(v.z, v.w);
        *(uint2*)(xs + row * LDX + c4 * 4) = p;
    }

    const int st_o = (w & 1) * 64 + lane;
    const int st_f = (w >> 1) * 64;
    const int st_h = w >> 1;
    const int go   = o0 + st_o;
    const bool ov  = go < NOUT;

    float rw[64];
    {
        const float* Wp = W + (size_t)st_f * NOUT + go;
        #pragma unroll
        for (int g = 0; g < 16; g++)
            #pragma unroll
            for (int c = 0; c < 4; c++)
                rw[g * 4 + c] = ov ? Wp[(size_t)(g * 4 + c) * NOUT] : 0.0f;
    }
    __syncthreads();

    short8 af[4][4];
    #pragma unroll
    for (int mt = 0; mt < 4; mt++)
        #pragma unroll
        for (int kk = 0; kk < 4; kk++)
            af[mt][kk] = *(const short8*)(xs + (wm * 64 + mt * 16 + l15) * LDX + kk * 32 + q * 8);

    floatx4 maxv[4][4];
    #pragma unroll
    for (int mt = 0; mt < 4; mt++)
        #pragma unroll
        for (int nt = 0; nt < 4; nt++)
            #pragma unroll
            for (int r = 0; r < 4; r++)
                maxv[mt][nt][r] = -INFINITY;

    for (int k = 0; k < NK; k++) {
        float sq = 0.0f;
        uint2 pk[16];
        #pragma unroll
        for (int g = 0; g < 16; g++) {
            float a0 = rw[g * 4 + 0], a1 = rw[g * 4 + 1];
            float a2 = rw[g * 4 + 2], a3 = rw[g * 4 + 3];
            sq = fmaf(a0, a0, sq); sq = fmaf(a1, a1, sq);
            sq = fmaf(a2, a2, sq); sq = fmaf(a3, a3, sq);
            pk[g].x = packbf(a0, a1);
            pk[g].y = packbf(a2, a3);
        }
        __syncthreads();
        #pragma unroll
        for (int g = 0; g < 16; g++)
            *(uint2*)(wt + st_o * LDX + st_f + g * 4) = pk[g];
        sqs[st_o][st_h] = sq;
        __syncthreads();

        if (k < NK - 1) {
            const float* Wn = W + ((size_t)(k + 1) * FIN + st_f) * NOUT + go;
            #pragma unroll
            for (int g = 0; g < 16; g++)
                #pragma unroll
                for (int c = 0; c < 4; c++)
                    rw[g * 4 + c] = ov ? Wn[(size_t)(g * 4 + c) * NOUT] : 0.0f;
        }

        float wv[4];
        #pragma unroll
        for (int nt = 0; nt < 4; nt++) {
            int col = wn * 64 + nt * 16 + l15;
            wv[nt] = 1.0f / fmaxf(sqrtf(sqs[col][0] + sqs[col][1]), 1e-12f);
        }

        #pragma unroll
        for (int h = 0; h < 2; h++) {
            floatx4 acc[4][2];
            #pragma unroll
            for (int mt = 0; mt < 4; mt++) {
                acc[mt][0] = (floatx4){0.f, 0.f, 0.f, 0.f};
                acc[mt][1] = (floatx4){0.f, 0.f, 0.f, 0.f};
            }
            #pragma unroll
            for (int kk = 0; kk < 4; kk++) {
                short8 bf0 = *(const short8*)(wt + (wn * 64 + (h * 2 + 0) * 16 + l15) * LDX + kk * 32 + q * 8);
                short8 bf1 = *(const short8*)(wt + (wn * 64 + (h * 2 + 1) * 16 + l15) * LDX + kk * 32 + q * 8);
                #pragma unroll
                for (int mt = 0; mt < 4; mt++) {
                    acc[mt][0] = __builtin_amdgcn_mfma_f32_16x16x32_bf16(af[mt][kk], bf0, acc[mt][0], 0, 0, 0);
                    acc[mt][1] = __builtin_amdgcn_mfma_f32_16x16x32_bf16(af[mt][kk], bf1, acc[mt][1], 0, 0, 0);
                }
            }
            #pragma unroll
            for (int mt = 0; mt < 4; mt++)
                #pragma unroll
                for (int n2 = 0; n2 < 2; n2++)
                    #pragma unroll
                    for (int r = 0; r < 4; r++)
                        maxv[mt][h * 2 + n2][r] =
                            fmaxf(maxv[mt][h * 2 + n2][r], acc[mt][n2][r] * wv[h * 2 + n2]);
        }
    }

    #pragma unroll
    for (int mt = 0; mt < 4; mt++) {
        #pragma unroll
        for (int rr = 0; rr < 4; rr++) {
            int row = r0 + wm * 64 + mt * 16 + q * 4 + rr;
            float xi = xinv[row];
            int lb = label[row];
            float m = -1e30f, s = 0.f;
            #pragma unroll
            for (int nt = 0; nt < 4; nt++) {
                int o = o0 + wn * 64 + nt * 16 + l15;
                if (o < NOUT) {
                    float c = maxv[mt][nt][rr] * xi;
                    if (o == lb) {
                        cosl[row] = c;
                    } else {
                        float l = 64.0f * fminf(fmaxf(c, -1.0f + 1e-6f), 1.0f - 1e-6f);
                        if (l > m) { s = s * __expf(m - l) + 1.0f; m = l; }
                        else       { s += __expf(l - m); }
                    }
                }
            }
            #pragma unroll
            for (int off = 1; off <= 8; off <<= 1) {
                float m2 = __shfl_xor(m, off);
                float s2 = __shfl_xor(s, off);
                float M = fmaxf(m, m2);
                s = s * __expf(m - M) + s2 * __expf(m2 - M);
                m = M;
            }
            if (l15 == 0) {
                partial[(size_t)row * NPART + jb * 4 + wn * 2 + 0] = make_float2(m, s);
                partial[(size_t)row * NPART + jb * 4 + wn * 2 + 1] = make_float2(-1e30f, 0.f);
            }
        }
    }
}

// ---------------------------------------------------------------------------
// Kernel C1: per-row combine + margin -> (loss, corr) per row. No atomics.
__global__ void finalize_rows(const float2* __restrict__ partial, const float* __restrict__ cosl,
                              const float* __restrict__ fa, const float* __restrict__ thr,
                              float2* __restrict__ rowres) {
    int w = threadIdx.x >> 6;
    int lane = threadIdx.x & 63;
    int b = blockIdx.x * 4 + w;
    float m = -1e30f, s = 0.0f;
    for (int j = lane; j < NPART; j += 64) {
        float2 p = partial[(size_t)b * NPART + j];
        float M = fmaxf(m, p.x);
        s = s * __expf(m - M) + p.y * __expf(p.x - M);
        m = M;
    }
    #pragma unroll
    for (int off = 1; off < 64; off <<= 1) {
        float m2 = __shfl_xor(m, off);
        float s2 = __shfl_xor(s, off);
        float M = fmaxf(m, m2);
        s = s * __expf(m - M) + s2 * __expf(m2 - M);
        m = M;
    }
    if (lane == 0) {
        float c = fminf(fmaxf(cosl[b], -1.0f + 1e-6f), 1.0f - 1e-6f);
        float theta = acosf(c);
        float ll = (theta > thr[b]) ? 64.0f * c : 64.0f * cosf(theta + fa[b]);
        float M = fmaxf(m, ll);
        float S = s * __expf(m - M) + __expf(ll - M);
        rowres[b] = make_float2(M + logf(S) - ll, (ll > m) ? 100.0f : 0.0f);
    }
}

// Kernel C2: deterministic tree reduce of 1024 rows -> 2 scalars.
__global__ void finalize_sum(const float2* __restrict__ rowres, float* __restrict__ out) {
    __shared__ float sl[1024];
    __shared__ float sc[1024];
    int b = threadIdx.x;
    float2 v = rowres[b];
    sl[b] = v.x;
    sc[b] = v.y;
    __syncthreads();
    for (int st = 512; st > 0; st >>= 1) {
        if (b < st) { sl[b] += sl[b + st]; sc[b] += sc[b + st]; }
        __syncthreads();
    }
    if (b == 0) {
        out[0] = sl[0] * (1.0f / 1024.0f);
        out[1] = sc[0] * (1.0f / 1024.0f);
    }
}

// ---------------------------------------------------------------------------
extern "C" void kernel_launch(void* const* d_in, const int* in_sizes, int n_in,
                              void* d_out, int out_size, void* d_ws, size_t ws_size,
                              hipStream_t stream) {
    const float* X      = (const float*)d_in[0];
    const float* factor = (const float*)d_in[1];
    const int*   label  = (const int*)d_in[2];
    const float* W      = (const float*)d_in[3];
    float* out = (float*)d_out;
    float* ws  = (float*)d_ws;

    float*  xinv = ws;                        // 1024
    float*  fa   = ws + 1024;                 // 1024
    float*  thr  = ws + 2048;                 // 1024
    float*  cosl = ws + 3072;                 // 1024
    float2* rowres = (float2*)(ws + 4096);    // 1024 float2
    float2* partial = (float2*)(ws + 6144);   // 1024 x NPART float2 (~2.6 MB)
    unsigned char* Wbf = (unsigned char*)d_ws + 4 * 1024 * 1024;  // 41.4 MB

    const size_t wbf_bytes = (size_t)NK * NCB * 16384;
    const size_t need = 4ull * 1024 * 1024 + wbf_bytes;

    if (ws_size >= need) {
        wconv<<<NK * NCB + 16, 256, 0, stream>>>(W, Wbf, X, factor, xinv, fa, thr);
        gemm_mx<<<2560, 256, 0, stream>>>(X, Wbf, label, xinv, partial, cosl);
    } else {
        rowprep<<<BB, 64, 0, stream>>>(X, factor, xinv, fa, thr);
        gemm_stats<<<640, 256, 0, stream>>>(X, W, label, xinv, partial, cosl);
    }
    finalize_rows<<<BB / 4, 256, 0, stream>>>(partial, cosl, fa, thr, rowres);
    finalize_sum<<<1, BB, 0, stream>>>(rowres, out);
}

// Round 10
// 215.388 us; speedup vs baseline: 1.2156x; 1.0125x over previous
//
#include <hip/hip_runtime.h>
#include <hip/hip_bf16.h>
#include <math.h>

#define BB    1024
#define FIN   128
#define NOUT  10000
#define NBLK  79          // 128-col strips (fallback path)
#define NCB   158         // 64-col blocks (fast path)
#define NK    16
#define NPART (NCB * 2)   // per (cb, wn) partials == NBLK*4
#define LDX   136         // LDS stride (shorts) for the X tile

typedef __attribute__((ext_vector_type(8))) short short8;
typedef __attribute__((ext_vector_type(4))) float floatx4;

__device__ __forceinline__ unsigned packbf(float a, float b) {
    __hip_bfloat162 h = __float22bfloat162_rn(make_float2(a, b));
    union { __hip_bfloat162 h2; unsigned u; } v;
    v.h2 = h;
    return v.u;
}

// async global->LDS, 16B per lane; LDS dest = wave-uniform base + lane*16.
__device__ __forceinline__ void async16(const void* g, void* l) {
    __builtin_amdgcn_global_load_lds(
        (const __attribute__((address_space(1))) unsigned int*)g,
        (__attribute__((address_space(3))) unsigned int*)l, 16, 0, 0);
}

// ---------------------------------------------------------------------------
// Kernel A (fallback path only): per-row input inverse-norm + margin params
__global__ void rowprep(const float* __restrict__ X, const float* __restrict__ factor,
                        float* __restrict__ xinv, float* __restrict__ fa_out,
                        float* __restrict__ thr_out) {
    int b = blockIdx.x;
    int lane = threadIdx.x;
    float v0 = X[b * FIN + lane];
    float v1 = X[b * FIN + 64 + lane];
    float s = v0 * v0 + v1 * v1;
    #pragma unroll
    for (int off = 32; off > 0; off >>= 1) s += __shfl_down(s, off);
    if (lane == 0) {
        float n = sqrtf(s);
        xinv[b] = 1.0f / fmaxf(n, 1e-12f);
        float fa = powf(1.5f, factor[b] * (1.0f / 12.0f)) * 0.5f;
        fa_out[b] = fa;
        thr_out[b] = (float)M_PI - fa;
    }
}

// ---------------------------------------------------------------------------
// Kernel W: one-time W conversion + rowprep (last 16 blocks). Unchanged r9.
// Wbf layout (fully linear for gemm): per (k, cb) a 16 KB region:
//   [wn(2)][n2(2)][kk(4)][lane(64)][16B],  lane = q*16 + l15,
// holding bf16( W[k][f][o] * winv[k][o] ) with
//   o = cb*64 + wn*32 + n2*16 + l15,  f = (kk*4+q)*8 .. +7.
__global__ __launch_bounds__(256) void wconv(
    const float* __restrict__ W, unsigned char* __restrict__ Wbf,
    const float* __restrict__ X, const float* __restrict__ factor,
    float* __restrict__ xinv, float* __restrict__ fa_out, float* __restrict__ thr_out) {

    __shared__ float xs2[128 * 64];   // [f][c] fp32 (32 KB)
    __shared__ uint4 wout[1024];      // packed 16 KB
    __shared__ float sq2[256];
    __shared__ float wis[64];

    const int tid = threadIdx.x;

    if (blockIdx.x >= NK * NCB) {
        int rb = blockIdx.x - NK * NCB;   // 0..15
        int w4 = tid >> 6, lane = tid & 63;
        for (int i = w4; i < 64; i += 4) {
            int row = rb * 64 + i;
            float v0 = X[row * FIN + lane];
            float v1 = X[row * FIN + 64 + lane];
            float s = v0 * v0 + v1 * v1;
            #pragma unroll
            for (int off = 32; off > 0; off >>= 1) s += __shfl_down(s, off);
            if (lane == 0) {
                xinv[row] = 1.0f / fmaxf(sqrtf(s), 1e-12f);
                float fa = powf(1.5f, factor[row] * (1.0f / 12.0f)) * 0.5f;
                fa_out[row] = fa;
                thr_out[row] = (float)M_PI - fa;
            }
        }
        return;
    }

    const int k  = blockIdx.x / NCB;
    const int cb = blockIdx.x - k * NCB;
    const int o0 = cb * 64;

    #pragma unroll
    for (int it = 0; it < 8; it++) {
        int idx = it * 256 + tid;      // float4 index 0..2047
        int f  = idx >> 4;
        int c4 = idx & 15;
        int o  = o0 + c4 * 4;
        float4 v = make_float4(0.f, 0.f, 0.f, 0.f);
        if (o < NOUT)
            v = *(const float4*)(W + ((size_t)k * FIN + f) * NOUT + o);
        *(float4*)(xs2 + f * 64 + c4 * 4) = v;
    }
    __syncthreads();

    {
        const int col = tid & 63;
        const int seg = tid >> 6;
        float s = 0.0f;
        #pragma unroll 8
        for (int f2 = 0; f2 < 32; f2++) {
            float x = xs2[(seg * 32 + f2) * 64 + col];
            s = fmaf(x, x, s);
        }
        sq2[tid] = s;
    }
    __syncthreads();
    if (tid < 64)
        wis[tid] = 1.0f / fmaxf(sqrtf(sq2[tid] + sq2[tid + 64] + sq2[tid + 128] + sq2[tid + 192]), 1e-12f);
    __syncthreads();

    {
        const int c   = tid >> 2;
        const int sub = tid & 3;
        const float wi = wis[c];
        const int wn  = c >> 5;
        const int n2  = (c >> 4) & 1;
        const int l15 = c & 15;
        #pragma unroll
        for (int i = 0; i < 4; i++) {
            int tc = sub * 4 + i;          // feature chunk: f = tc*8..tc*8+7
            int kk = tc >> 2;
            int q  = tc & 3;
            float v0 = xs2[(tc * 8 + 0) * 64 + c] * wi;
            float v1 = xs2[(tc * 8 + 1) * 64 + c] * wi;
            float v2 = xs2[(tc * 8 + 2) * 64 + c] * wi;
            float v3 = xs2[(tc * 8 + 3) * 64 + c] * wi;
            float v4 = xs2[(tc * 8 + 4) * 64 + c] * wi;
            float v5 = xs2[(tc * 8 + 5) * 64 + c] * wi;
            float v6 = xs2[(tc * 8 + 6) * 64 + c] * wi;
            float v7 = xs2[(tc * 8 + 7) * 64 + c] * wi;
            uint4 u;
            u.x = packbf(v0, v1);
            u.y = packbf(v2, v3);
            u.z = packbf(v4, v5);
            u.w = packbf(v6, v7);
            wout[wn * 512 + n2 * 256 + kk * 64 + q * 16 + l15] = u;
        }
    }
    __syncthreads();

    unsigned char* dst = Wbf + ((size_t)k * NCB + cb) * 16384;
    #pragma unroll
    for (int i = 0; i < 4; i++) {
        int idx = i * 256 + tid;
        *(uint4*)(dst + (size_t)idx * 16) = wout[idx];
    }
}

// ---------------------------------------------------------------------------
// Kernel B: MFMA GEMM + max-over-k + partial online-softmax.
// 512 threads = 8 waves (4m x 2n grid of 32x32 wave tiles), block tile
// 128 rows x 64 cols. B staged ONCE per k-step into LDS via async16
// (16 KB unique, zero intra-block redundancy; 8 y-blocks/cb instead of 16
// halves cross-block redundancy too: B L2 traffic 1.3 GB -> ~0.4 GB).
__global__ __launch_bounds__(512, 2) void gemm_mx(
    const float* __restrict__ X, const unsigned char* __restrict__ Wbf,
    const int* __restrict__ label, const float* __restrict__ xinv,
    float2* __restrict__ partial, float* __restrict__ cosl) {

    __shared__ union {
        short xs[128 * LDX];   // 34816 B, X staging
        short bb[2][8192];     // 2 x 16 KB B buffers
    } u;

    const int tid  = threadIdx.x;
    const int lane = tid & 63;
    const int w    = tid >> 6;     // 0..7
    const int l15  = lane & 15;
    const int q    = lane >> 4;
    const int wm   = w & 3;        // 4 m-slots (32 rows each)
    const int wn   = w >> 2;       // 2 n-slots (32 cols each)

    // XCD-aware decode: ids {group*64 + y*8 + xcd} -> cb = group*8 + xcd
    const int id    = blockIdx.x;
    const int group = id >> 6;
    const int sub   = id & 63;
    const int cb    = group * 8 + (sub & 7);
    const int y     = sub >> 3;            // 0..7
    if (cb >= NCB) return;
    const int r0 = y * 128;
    const int o0 = cb * 64;

    // ---- stage X tile (128 rows) as bf16 with xinv folded ----
    #pragma unroll
    for (int it = 0; it < 8; it++) {
        int idx = it * 512 + tid;      // float4 index 0..4095
        int row = idx >> 5;
        int c4  = idx & 31;
        const float4 v = *(const float4*)(X + (size_t)(r0 + row) * FIN + c4 * 4);
        float xi = xinv[r0 + row];
        uint2 p;
        p.x = packbf(v.x * xi, v.y * xi);
        p.y = packbf(v.z * xi, v.w * xi);
        *(uint2*)(u.xs + row * LDX + c4 * 4) = p;
    }
    __syncthreads();

    short8 af[2][4];
    #pragma unroll
    for (int mt = 0; mt < 2; mt++)
        #pragma unroll
        for (int kk = 0; kk < 4; kk++)
            af[mt][kk] = *(const short8*)(u.xs + (wm * 32 + mt * 16 + l15) * LDX + kk * 32 + q * 8);
    __syncthreads();   // X area now reusable as B buffers

    // per-step B staging: 16 KB; wave w loads 2 KB (2 async16 calls)
    auto issue = [&](int k) {
        const unsigned char* g = Wbf + ((size_t)k * NCB + cb) * 16384
                                 + (size_t)w * 2048 + (size_t)lane * 16;
        short* d = u.bb[k & 1] + w * 1024;
        async16(g, d);
        async16(g + 1024, d + 512);
    };

    issue(0);

    floatx4 maxv[2][2];
    #pragma unroll
    for (int mt = 0; mt < 2; mt++)
        #pragma unroll
        for (int n2 = 0; n2 < 2; n2++)
            #pragma unroll
            for (int r = 0; r < 4; r++)
                maxv[mt][n2][r] = -INFINITY;

    for (int k = 0; k < NK; k++) {
        __syncthreads();   // loads(k) landed; prior buffer reads done
        if (k < NK - 1) issue(k + 1);
        const short* wt = u.bb[k & 1];

        floatx4 acc[2][2];
        #pragma unroll
        for (int mt = 0; mt < 2; mt++)
            #pragma unroll
            for (int n2 = 0; n2 < 2; n2++)
                acc[mt][n2] = (floatx4){0.f, 0.f, 0.f, 0.f};
        #pragma unroll
        for (int kk = 0; kk < 4; kk++) {
            short8 bf[2];
            #pragma unroll
            for (int n2 = 0; n2 < 2; n2++)
                bf[n2] = *(const short8*)(wt + wn * 4096 + n2 * 2048 + kk * 512 + lane * 8);
            #pragma unroll
            for (int mt = 0; mt < 2; mt++)
                #pragma unroll
                for (int n2 = 0; n2 < 2; n2++)
                    acc[mt][n2] = __builtin_amdgcn_mfma_f32_16x16x32_bf16(
                        af[mt][kk], bf[n2], acc[mt][n2], 0, 0, 0);
        }
        #pragma unroll
        for (int mt = 0; mt < 2; mt++)
            #pragma unroll
            for (int n2 = 0; n2 < 2; n2++)
                #pragma unroll
                for (int r = 0; r < 4; r++)
                    maxv[mt][n2][r] = fmaxf(maxv[mt][n2][r], acc[mt][n2][r]);
    }

    // ---- epilogue: per-row partial online-softmax (label col excluded) ----
    #pragma unroll
    for (int mt = 0; mt < 2; mt++) {
        #pragma unroll
        for (int rr = 0; rr < 4; rr++) {
            int row = r0 + wm * 32 + mt * 16 + q * 4 + rr;
            int lb = label[row];
            float m = -1e30f, s = 0.f;
            #pragma unroll
            for (int n2 = 0; n2 < 2; n2++) {
                int o = o0 + wn * 32 + n2 * 16 + l15;
                if (o < NOUT) {
                    float c = maxv[mt][n2][rr];
                    if (o == lb) {
                        cosl[row] = c;   // unique writer grid-wide
                    } else {
                        float l = 64.0f * fminf(fmaxf(c, -1.0f + 1e-6f), 1.0f - 1e-6f);
                        if (l > m) { s = s * __expf(m - l) + 1.0f; m = l; }
                        else       { s += __expf(l - m); }
                    }
                }
            }
            #pragma unroll
            for (int off = 1; off <= 8; off <<= 1) {
                float m2 = __shfl_xor(m, off);
                float s2 = __shfl_xor(s, off);
                float M = fmaxf(m, m2);
                s = s * __expf(m - M) + s2 * __expf(m2 - M);
                m = M;
            }
            if (l15 == 0)
                partial[(size_t)row * NPART + cb * 2 + wn] = make_float2(m, s);
        }
    }
}

// ---------------------------------------------------------------------------
// Fallback GEMM (round-3 path) used when ws_size can't hold Wbf.
__global__ __launch_bounds__(256, 2) void gemm_stats(
    const float* __restrict__ X, const float* __restrict__ W,
    const int* __restrict__ label, const float* __restrict__ xinv,
    float2* __restrict__ partial, float* __restrict__ cosl) {

    __shared__ short xs[128 * LDX];
    __shared__ short wt[128 * LDX];
    __shared__ float sqs[128][2];

    const int tid  = threadIdx.x;
    const int lane = tid & 63;
    const int w    = tid >> 6;
    const int l15  = lane & 15;
    const int q    = lane >> 4;
    const int wm   = w & 1;
    const int wn   = w >> 1;

    const int id    = blockIdx.x;
    const int group = id >> 6;
    const int sub   = id & 63;
    const int jb    = group * 8 + (sub & 7);
    const int y     = sub >> 3;
    if (jb >= NBLK) return;
    const int r0 = y * 128;
    const int o0 = jb * 128;

    #pragma unroll
    for (int it = 0; it < 16; it++) {
        int idx = it * 256 + tid;
        int row = idx >> 5;
        int c4  = idx & 31;
        const float4 v = *(const float4*)(X + (size_t)(r0 + row) * FIN + c4 * 4);
        uint2 p;
        p.x = packbf(v.x, v.y);
        p.y = packbf(v.z, v.w);
        *(uint2*)(xs + row * LDX + c4 * 4) = p;
    }

    const int st_o = (w & 1) * 64 + lane;
    const int st_f = (w >> 1) * 64;
    const int st_h = w >> 1;
    const int go   = o0 + st_o;
    const bool ov  = go < NOUT;

    float rw[64];
    {
        const float* Wp = W + (size_t)st_f * NOUT + go;
        #pragma unroll
        for (int g = 0; g < 16; g++)
            #pragma unroll
            for (int c = 0; c < 4; c++)
                rw[g * 4 + c] = ov ? Wp[(size_t)(g * 4 + c) * NOUT] : 0.0f;
    }
    __syncthreads();

    short8 af[4][4];
    #pragma unroll
    for (int mt = 0; mt < 4; mt++)
        #pragma unroll
        for (int kk = 0; kk < 4; kk++)
            af[mt][kk] = *(const short8*)(xs + (wm * 64 + mt * 16 + l15) * LDX + kk * 32 + q * 8);

    floatx4 maxv[4][4];
    #pragma unroll
    for (int mt = 0; mt < 4; mt++)
        #pragma unroll
        for (int nt = 0; nt < 4; nt++)
            #pragma unroll
            for (int r = 0; r < 4; r++)
                maxv[mt][nt][r] = -INFINITY;

    for (int k = 0; k < NK; k++) {
        float sq = 0.0f;
        uint2 pk[16];
        #pragma unroll
        for (int g = 0; g < 16; g++) {
            float a0 = rw[g * 4 + 0], a1 = rw[g * 4 + 1];
            float a2 = rw[g * 4 + 2], a3 = rw[g * 4 + 3];
            sq = fmaf(a0, a0, sq); sq = fmaf(a1, a1, sq);
            sq = fmaf(a2, a2, sq); sq = fmaf(a3, a3, sq);
            pk[g].x = packbf(a0, a1);
            pk[g].y = packbf(a2, a3);
        }
        __syncthreads();
        #pragma unroll
        for (int g = 0; g < 16; g++)
            *(uint2*)(wt + st_o * LDX + st_f + g * 4) = pk[g];
        sqs[st_o][st_h] = sq;
        __syncthreads();

        if (k < NK - 1) {
            const float* Wn = W + ((size_t)(k + 1) * FIN + st_f) * NOUT + go;
            #pragma unroll
            for (int g = 0; g < 16; g++)
                #pragma unroll
                for (int c = 0; c < 4; c++)
                    rw[g * 4 + c] = ov ? Wn[(size_t)(g * 4 + c) * NOUT] : 0.0f;
        }

        float wv[4];
        #pragma unroll
        for (int nt = 0; nt < 4; nt++) {
            int col = wn * 64 + nt * 16 + l15;
            wv[nt] = 1.0f / fmaxf(sqrtf(sqs[col][0] + sqs[col][1]), 1e-12f);
        }

        #pragma unroll
        for (int h = 0; h < 2; h++) {
            floatx4 acc[4][2];
            #pragma unroll
            for (int mt = 0; mt < 4; mt++) {
                acc[mt][0] = (floatx4){0.f, 0.f, 0.f, 0.f};
                acc[mt][1] = (floatx4){0.f, 0.f, 0.f, 0.f};
            }
            #pragma unroll
            for (int kk = 0; kk < 4; kk++) {
                short8 bf0 = *(const short8*)(wt + (wn * 64 + (h * 2 + 0) * 16 + l15) * LDX + kk * 32 + q * 8);
                short8 bf1 = *(const short8*)(wt + (wn * 64 + (h * 2 + 1) * 16 + l15) * LDX + kk * 32 + q * 8);
                #pragma unroll
                for (int mt = 0; mt < 4; mt++) {
                    acc[mt][0] = __builtin_amdgcn_mfma_f32_16x16x32_bf16(af[mt][kk], bf0, acc[mt][0], 0, 0, 0);
                    acc[mt][1] = __builtin_amdgcn_mfma_f32_16x16x32_bf16(af[mt][kk], bf1, acc[mt][1], 0, 0, 0);
                }
            }
            #pragma unroll
            for (int mt = 0; mt < 4; mt++)
                #pragma unroll
                for (int n2 = 0; n2 < 2; n2++)
                    #pragma unroll
                    for (int r = 0; r < 4; r++)
                        maxv[mt][h * 2 + n2][r] =
                            fmaxf(maxv[mt][h * 2 + n2][r], acc[mt][n2][r] * wv[h * 2 + n2]);
        }
    }

    #pragma unroll
    for (int mt = 0; mt < 4; mt++) {
        #pragma unroll
        for (int rr = 0; rr < 4; rr++) {
            int row = r0 + wm * 64 + mt * 16 + q * 4 + rr;
            float xi = xinv[row];
            int lb = label[row];
            float m = -1e30f, s = 0.f;
            #pragma unroll
            for (int nt = 0; nt < 4; nt++) {
                int o = o0 + wn * 64 + nt * 16 + l15;
                if (o < NOUT) {
                    float c = maxv[mt][nt][rr] * xi;
                    if (o == lb) {
                        cosl[row] = c;
                    } else {
                        float l = 64.0f * fminf(fmaxf(c, -1.0f + 1e-6f), 1.0f - 1e-6f);
                        if (l > m) { s = s * __expf(m - l) + 1.0f; m = l; }
                        else       { s += __expf(l - m); }
                    }
                }
            }
            #pragma unroll
            for (int off = 1; off <= 8; off <<= 1) {
                float m2 = __shfl_xor(m, off);
                float s2 = __shfl_xor(s, off);
                float M = fmaxf(m, m2);
                s = s * __expf(m - M) + s2 * __expf(m2 - M);
                m = M;
            }
            if (l15 == 0) {
                partial[(size_t)row * NPART + jb * 4 + wn * 2 + 0] = make_float2(m, s);
                partial[(size_t)row * NPART + jb * 4 + wn * 2 + 1] = make_float2(-1e30f, 0.f);
            }
        }
    }
}

// ---------------------------------------------------------------------------
// Kernel C1: per-row combine + margin -> (loss, corr) per row. No atomics.
__global__ void finalize_rows(const float2* __restrict__ partial, const float* __restrict__ cosl,
                              const float* __restrict__ fa, const float* __restrict__ thr,
                              float2* __restrict__ rowres) {
    int w = threadIdx.x >> 6;
    int lane = threadIdx.x & 63;
    int b = blockIdx.x * 4 + w;
    float m = -1e30f, s = 0.0f;
    for (int j = lane; j < NPART; j += 64) {
        float2 p = partial[(size_t)b * NPART + j];
        float M = fmaxf(m, p.x);
        s = s * __expf(m - M) + p.y * __expf(p.x - M);
        m = M;
    }
    #pragma unroll
    for (int off = 1; off < 64; off <<= 1) {
        float m2 = __shfl_xor(m, off);
        float s2 = __shfl_xor(s, off);
        float M = fmaxf(m, m2);
        s = s * __expf(m - M) + s2 * __expf(m2 - M);
        m = M;
    }
    if (lane == 0) {
        float c = fminf(fmaxf(cosl[b], -1.0f + 1e-6f), 1.0f - 1e-6f);
        float theta = acosf(c);
        float ll = (theta > thr[b]) ? 64.0f * c : 64.0f * cosf(theta + fa[b]);
        float M = fmaxf(m, ll);
        float S = s * __expf(m - M) + __expf(ll - M);
        rowres[b] = make_float2(M + logf(S) - ll, (ll > m) ? 100.0f : 0.0f);
    }
}

// Kernel C2: deterministic tree reduce of 1024 rows -> 2 scalars.
__global__ void finalize_sum(const float2* __restrict__ rowres, float* __restrict__ out) {
    __shared__ float sl[1024];
    __shared__ float sc[1024];
    int b = threadIdx.x;
    float2 v = rowres[b];
    sl[b] = v.x;
    sc[b] = v.y;
    __syncthreads();
    for (int st = 512; st > 0; st >>= 1) {
        if (b < st) { sl[b] += sl[b + st]; sc[b] += sc[b + st]; }
        __syncthreads();
    }
    if (b == 0) {
        out[0] = sl[0] * (1.0f / 1024.0f);
        out[1] = sc[0] * (1.0f / 1024.0f);
    }
}

// ---------------------------------------------------------------------------
extern "C" void kernel_launch(void* const* d_in, const int* in_sizes, int n_in,
                              void* d_out, int out_size, void* d_ws, size_t ws_size,
                              hipStream_t stream) {
    const float* X      = (const float*)d_in[0];
    const float* factor = (const float*)d_in[1];
    const int*   label  = (const int*)d_in[2];
    const float* W      = (const float*)d_in[3];
    float* out = (float*)d_out;
    float* ws  = (float*)d_ws;

    float*  xinv = ws;                        // 1024
    float*  fa   = ws + 1024;                 // 1024
    float*  thr  = ws + 2048;                 // 1024
    float*  cosl = ws + 3072;                 // 1024
    float2* rowres = (float2*)(ws + 4096);    // 1024 float2
    float2* partial = (float2*)(ws + 6144);   // 1024 x NPART float2 (~2.6 MB)
    unsigned char* Wbf = (unsigned char*)d_ws + 4 * 1024 * 1024;  // 41.4 MB

    const size_t wbf_bytes = (size_t)NK * NCB * 16384;
    const size_t need = 4ull * 1024 * 1024 + wbf_bytes;

    if (ws_size >= need) {
        wconv<<<NK * NCB + 16, 256, 0, stream>>>(W, Wbf, X, factor, xinv, fa, thr);
        gemm_mx<<<1280, 512, 0, stream>>>(X, Wbf, label, xinv, partial, cosl);
    } else {
        rowprep<<<BB, 64, 0, stream>>>(X, factor, xinv, fa, thr);
        gemm_stats<<<640, 256, 0, stream>>>(X, W, label, xinv, partial, cosl);
    }
    finalize_rows<<<BB / 4, 256, 0, stream>>>(partial, cosl, fa, thr, rowres);
    finalize_sum<<<1, BB, 0, stream>>>(rowres, out);
}

// Round 11
// 210.207 us; speedup vs baseline: 1.2456x; 1.0247x over previous
//
#include <hip/hip_runtime.h>
#include <hip/hip_bf16.h>
#include <math.h>

#define BB    1024
#define FIN   128
#define NOUT  10000
#define NBLK  79          // 128-col strips (fallback path)
#define NCB   158         // 64-col blocks (fast path)
#define NK    16
#define NPART (NCB * 2)   // per (cb, wn) partials == NBLK*4
#define LDX   136         // LDS stride (shorts) for the X tile

typedef __attribute__((ext_vector_type(8))) short short8;
typedef __attribute__((ext_vector_type(4))) float floatx4;

__device__ __forceinline__ unsigned packbf(float a, float b) {
    __hip_bfloat162 h = __float22bfloat162_rn(make_float2(a, b));
    union { __hip_bfloat162 h2; unsigned u; } v;
    v.h2 = h;
    return v.u;
}

// async global->LDS, 16B per lane; LDS dest = wave-uniform base + lane*16.
__device__ __forceinline__ void async16(const void* g, void* l) {
    __builtin_amdgcn_global_load_lds(
        (const __attribute__((address_space(1))) unsigned int*)g,
        (__attribute__((address_space(3))) unsigned int*)l, 16, 0, 0);
}

// ---------------------------------------------------------------------------
// Kernel A (fallback path only): per-row input inverse-norm + margin params
__global__ void rowprep(const float* __restrict__ X, const float* __restrict__ factor,
                        float* __restrict__ xinv, float* __restrict__ fa_out,
                        float* __restrict__ thr_out) {
    int b = blockIdx.x;
    int lane = threadIdx.x;
    float v0 = X[b * FIN + lane];
    float v1 = X[b * FIN + 64 + lane];
    float s = v0 * v0 + v1 * v1;
    #pragma unroll
    for (int off = 32; off > 0; off >>= 1) s += __shfl_down(s, off);
    if (lane == 0) {
        float n = sqrtf(s);
        xinv[b] = 1.0f / fmaxf(n, 1e-12f);
        float fa = powf(1.5f, factor[b] * (1.0f / 12.0f)) * 0.5f;
        fa_out[b] = fa;
        thr_out[b] = (float)M_PI - fa;
    }
}

// ---------------------------------------------------------------------------
// Kernel W: one-time W conversion + rowprep (last 16 blocks). Unchanged r9/r10.
// Wbf layout (fully linear for gemm): per (k, cb) a 16 KB region:
//   [wn(2)][n2(2)][kk(4)][lane(64)][16B],  lane = q*16 + l15,
// holding bf16( W[k][f][o] * winv[k][o] ) with
//   o = cb*64 + wn*32 + n2*16 + l15,  f = (kk*4+q)*8 .. +7.
__global__ __launch_bounds__(256) void wconv(
    const float* __restrict__ W, unsigned char* __restrict__ Wbf,
    const float* __restrict__ X, const float* __restrict__ factor,
    float* __restrict__ xinv, float* __restrict__ fa_out, float* __restrict__ thr_out) {

    __shared__ float xs2[128 * 64];   // [f][c] fp32 (32 KB)
    __shared__ uint4 wout[1024];      // packed 16 KB
    __shared__ float sq2[256];
    __shared__ float wis[64];

    const int tid = threadIdx.x;

    if (blockIdx.x >= NK * NCB) {
        int rb = blockIdx.x - NK * NCB;   // 0..15
        int w4 = tid >> 6, lane = tid & 63;
        for (int i = w4; i < 64; i += 4) {
            int row = rb * 64 + i;
            float v0 = X[row * FIN + lane];
            float v1 = X[row * FIN + 64 + lane];
            float s = v0 * v0 + v1 * v1;
            #pragma unroll
            for (int off = 32; off > 0; off >>= 1) s += __shfl_down(s, off);
            if (lane == 0) {
                xinv[row] = 1.0f / fmaxf(sqrtf(s), 1e-12f);
                float fa = powf(1.5f, factor[row] * (1.0f / 12.0f)) * 0.5f;
                fa_out[row] = fa;
                thr_out[row] = (float)M_PI - fa;
            }
        }
        return;
    }

    const int k  = blockIdx.x / NCB;
    const int cb = blockIdx.x - k * NCB;
    const int o0 = cb * 64;

    #pragma unroll
    for (int it = 0; it < 8; it++) {
        int idx = it * 256 + tid;      // float4 index 0..2047
        int f  = idx >> 4;
        int c4 = idx & 15;
        int o  = o0 + c4 * 4;
        float4 v = make_float4(0.f, 0.f, 0.f, 0.f);
        if (o < NOUT)
            v = *(const float4*)(W + ((size_t)k * FIN + f) * NOUT + o);
        *(float4*)(xs2 + f * 64 + c4 * 4) = v;
    }
    __syncthreads();

    {
        const int col = tid & 63;
        const int seg = tid >> 6;
        float s = 0.0f;
        #pragma unroll 8
        for (int f2 = 0; f2 < 32; f2++) {
            float x = xs2[(seg * 32 + f2) * 64 + col];
            s = fmaf(x, x, s);
        }
        sq2[tid] = s;
    }
    __syncthreads();
    if (tid < 64)
        wis[tid] = 1.0f / fmaxf(sqrtf(sq2[tid] + sq2[tid + 64] + sq2[tid + 128] + sq2[tid + 192]), 1e-12f);
    __syncthreads();

    {
        const int c   = tid >> 2;
        const int sub = tid & 3;
        const float wi = wis[c];
        const int wn  = c >> 5;
        const int n2  = (c >> 4) & 1;
        const int l15 = c & 15;
        #pragma unroll
        for (int i = 0; i < 4; i++) {
            int tc = sub * 4 + i;          // feature chunk: f = tc*8..tc*8+7
            int kk = tc >> 2;
            int q  = tc & 3;
            float v0 = xs2[(tc * 8 + 0) * 64 + c] * wi;
            float v1 = xs2[(tc * 8 + 1) * 64 + c] * wi;
            float v2 = xs2[(tc * 8 + 2) * 64 + c] * wi;
            float v3 = xs2[(tc * 8 + 3) * 64 + c] * wi;
            float v4 = xs2[(tc * 8 + 4) * 64 + c] * wi;
            float v5 = xs2[(tc * 8 + 5) * 64 + c] * wi;
            float v6 = xs2[(tc * 8 + 6) * 64 + c] * wi;
            float v7 = xs2[(tc * 8 + 7) * 64 + c] * wi;
            uint4 u;
            u.x = packbf(v0, v1);
            u.y = packbf(v2, v3);
            u.z = packbf(v4, v5);
            u.w = packbf(v6, v7);
            wout[wn * 512 + n2 * 256 + kk * 64 + q * 16 + l15] = u;
        }
    }
    __syncthreads();

    unsigned char* dst = Wbf + ((size_t)k * NCB + cb) * 16384;
    #pragma unroll
    for (int i = 0; i < 4; i++) {
        int idx = i * 256 + tid;
        *(uint4*)(dst + (size_t)idx * 16) = wout[idx];
    }
}

// ---------------------------------------------------------------------------
// Kernel B: MFMA GEMM + max-over-k + partial FIXED-REFERENCE softmax stats.
// Structure identical to r10 (512 thr, 128x64 tile, async16-dbuf LDS B).
// NEW: softmax partials use fixed reference m0=64 (logits bounded by 64):
//   s = sum exp(l - 64), m = max l   -> no online rescaling, no exp in the
// reduction (plain add/fmax). partial=(m, s_fixed64).
__global__ __launch_bounds__(512, 2) void gemm_mx(
    const float* __restrict__ X, const unsigned char* __restrict__ Wbf,
    const int* __restrict__ label, const float* __restrict__ xinv,
    float2* __restrict__ partial, float* __restrict__ cosl) {

    __shared__ union {
        short xs[128 * LDX];   // 34816 B, X staging
        short bb[2][8192];     // 2 x 16 KB B buffers
    } u;

    const int tid  = threadIdx.x;
    const int lane = tid & 63;
    const int w    = tid >> 6;     // 0..7
    const int l15  = lane & 15;
    const int q    = lane >> 4;
    const int wm   = w & 3;        // 4 m-slots (32 rows each)
    const int wn   = w >> 2;       // 2 n-slots (32 cols each)

    // XCD-aware decode: ids {group*64 + y*8 + xcd} -> cb = group*8 + xcd
    const int id    = blockIdx.x;
    const int group = id >> 6;
    const int sub   = id & 63;
    const int cb    = group * 8 + (sub & 7);
    const int y     = sub >> 3;            // 0..7
    if (cb >= NCB) return;
    const int r0 = y * 128;
    const int o0 = cb * 64;

    // ---- stage X tile (128 rows) as bf16 with xinv folded ----
    #pragma unroll
    for (int it = 0; it < 8; it++) {
        int idx = it * 512 + tid;      // float4 index 0..4095
        int row = idx >> 5;
        int c4  = idx & 31;
        const float4 v = *(const float4*)(X + (size_t)(r0 + row) * FIN + c4 * 4);
        float xi = xinv[r0 + row];
        uint2 p;
        p.x = packbf(v.x * xi, v.y * xi);
        p.y = packbf(v.z * xi, v.w * xi);
        *(uint2*)(u.xs + row * LDX + c4 * 4) = p;
    }
    __syncthreads();

    short8 af[2][4];
    #pragma unroll
    for (int mt = 0; mt < 2; mt++)
        #pragma unroll
        for (int kk = 0; kk < 4; kk++)
            af[mt][kk] = *(const short8*)(u.xs + (wm * 32 + mt * 16 + l15) * LDX + kk * 32 + q * 8);
    __syncthreads();   // X area now reusable as B buffers

    // per-step B staging: 16 KB; wave w loads 2 KB (2 async16 calls)
    auto issue = [&](int k) {
        const unsigned char* g = Wbf + ((size_t)k * NCB + cb) * 16384
                                 + (size_t)w * 2048 + (size_t)lane * 16;
        short* d = u.bb[k & 1] + w * 1024;
        async16(g, d);
        async16(g + 1024, d + 512);
    };

    issue(0);

    floatx4 maxv[2][2];
    #pragma unroll
    for (int mt = 0; mt < 2; mt++)
        #pragma unroll
        for (int n2 = 0; n2 < 2; n2++)
            #pragma unroll
            for (int r = 0; r < 4; r++)
                maxv[mt][n2][r] = -INFINITY;

    for (int k = 0; k < NK; k++) {
        __syncthreads();   // loads(k) landed; prior buffer reads done
        if (k < NK - 1) issue(k + 1);
        const short* wt = u.bb[k & 1];

        floatx4 acc[2][2];
        #pragma unroll
        for (int mt = 0; mt < 2; mt++)
            #pragma unroll
            for (int n2 = 0; n2 < 2; n2++)
                acc[mt][n2] = (floatx4){0.f, 0.f, 0.f, 0.f};
        #pragma unroll
        for (int kk = 0; kk < 4; kk++) {
            short8 bf[2];
            #pragma unroll
            for (int n2 = 0; n2 < 2; n2++)
                bf[n2] = *(const short8*)(wt + wn * 4096 + n2 * 2048 + kk * 512 + lane * 8);
            #pragma unroll
            for (int mt = 0; mt < 2; mt++)
                #pragma unroll
                for (int n2 = 0; n2 < 2; n2++)
                    acc[mt][n2] = __builtin_amdgcn_mfma_f32_16x16x32_bf16(
                        af[mt][kk], bf[n2], acc[mt][n2], 0, 0, 0);
        }
        #pragma unroll
        for (int mt = 0; mt < 2; mt++)
            #pragma unroll
            for (int n2 = 0; n2 < 2; n2++)
                #pragma unroll
                for (int r = 0; r < 4; r++)
                    maxv[mt][n2][r] = fmaxf(maxv[mt][n2][r], acc[mt][n2][r]);
    }

    // ---- epilogue: fixed-reference partial softmax (label col excluded) ----
    #pragma unroll
    for (int mt = 0; mt < 2; mt++) {
        #pragma unroll
        for (int rr = 0; rr < 4; rr++) {
            int row = r0 + wm * 32 + mt * 16 + q * 4 + rr;
            int lb = label[row];
            float m = -1e30f, s = 0.f;
            #pragma unroll
            for (int n2 = 0; n2 < 2; n2++) {
                int o = o0 + wn * 32 + n2 * 16 + l15;
                if (o < NOUT) {
                    float c = maxv[mt][n2][rr];
                    if (o == lb) {
                        cosl[row] = c;   // unique writer grid-wide
                    } else {
                        float l = 64.0f * fminf(fmaxf(c, -1.0f + 1e-6f), 1.0f - 1e-6f);
                        s += __expf(l - 64.0f);
                        m = fmaxf(m, l);
                    }
                }
            }
            // plain sum/max reduction across the 16 lanes (no exp)
            #pragma unroll
            for (int off = 1; off <= 8; off <<= 1) {
                s += __shfl_xor(s, off);
                m = fmaxf(m, __shfl_xor(m, off));
            }
            if (l15 == 0)
                partial[(size_t)row * NPART + cb * 2 + wn] = make_float2(m, s);
        }
    }
}

// ---------------------------------------------------------------------------
// Fallback GEMM (round-3 path) used when ws_size can't hold Wbf.
// Epilogue updated to fixed-reference partials (matches finalize_rows).
__global__ __launch_bounds__(256, 2) void gemm_stats(
    const float* __restrict__ X, const float* __restrict__ W,
    const int* __restrict__ label, const float* __restrict__ xinv,
    float2* __restrict__ partial, float* __restrict__ cosl) {

    __shared__ short xs[128 * LDX];
    __shared__ short wt[128 * LDX];
    __shared__ float sqs[128][2];

    const int tid  = threadIdx.x;
    const int lane = tid & 63;
    const int w    = tid >> 6;
    const int l15  = lane & 15;
    const int q    = lane >> 4;
    const int wm   = w & 1;
    const int wn   = w >> 1;

    const int id    = blockIdx.x;
    const int group = id >> 6;
    const int sub   = id & 63;
    const int jb    = group * 8 + (sub & 7);
    const int y     = sub >> 3;
    if (jb >= NBLK) return;
    const int r0 = y * 128;
    const int o0 = jb * 128;

    #pragma unroll
    for (int it = 0; it < 16; it++) {
        int idx = it * 256 + tid;
        int row = idx >> 5;
        int c4  = idx & 31;
        const float4 v = *(const float4*)(X + (size_t)(r0 + row) * FIN + c4 * 4);
        uint2 p;
        p.x = packbf(v.x, v.y);
        p.y = packbf(v.z, v.w);
        *(uint2*)(xs + row * LDX + c4 * 4) = p;
    }

    const int st_o = (w & 1) * 64 + lane;
    const int st_f = (w >> 1) * 64;
    const int st_h = w >> 1;
    const int go   = o0 + st_o;
    const bool ov  = go < NOUT;

    float rw[64];
    {
        const float* Wp = W + (size_t)st_f * NOUT + go;
        #pragma unroll
        for (int g = 0; g < 16; g++)
            #pragma unroll
            for (int c = 0; c < 4; c++)
                rw[g * 4 + c] = ov ? Wp[(size_t)(g * 4 + c) * NOUT] : 0.0f;
    }
    __syncthreads();

    short8 af[4][4];
    #pragma unroll
    for (int mt = 0; mt < 4; mt++)
        #pragma unroll
        for (int kk = 0; kk < 4; kk++)
            af[mt][kk] = *(const short8*)(xs + (wm * 64 + mt * 16 + l15) * LDX + kk * 32 + q * 8);

    floatx4 maxv[4][4];
    #pragma unroll
    for (int mt = 0; mt < 4; mt++)
        #pragma unroll
        for (int nt = 0; nt < 4; nt++)
            #pragma unroll
            for (int r = 0; r < 4; r++)
                maxv[mt][nt][r] = -INFINITY;

    for (int k = 0; k < NK; k++) {
        float sq = 0.0f;
        uint2 pk[16];
        #pragma unroll
        for (int g = 0; g < 16; g++) {
            float a0 = rw[g * 4 + 0], a1 = rw[g * 4 + 1];
            float a2 = rw[g * 4 + 2], a3 = rw[g * 4 + 3];
            sq = fmaf(a0, a0, sq); sq = fmaf(a1, a1, sq);
            sq = fmaf(a2, a2, sq); sq = fmaf(a3, a3, sq);
            pk[g].x = packbf(a0, a1);
            pk[g].y = packbf(a2, a3);
        }
        __syncthreads();
        #pragma unroll
        for (int g = 0; g < 16; g++)
            *(uint2*)(wt + st_o * LDX + st_f + g * 4) = pk[g];
        sqs[st_o][st_h] = sq;
        __syncthreads();

        if (k < NK - 1) {
            const float* Wn = W + ((size_t)(k + 1) * FIN + st_f) * NOUT + go;
            #pragma unroll
            for (int g = 0; g < 16; g++)
                #pragma unroll
                for (int c = 0; c < 4; c++)
                    rw[g * 4 + c] = ov ? Wn[(size_t)(g * 4 + c) * NOUT] : 0.0f;
        }

        float wv[4];
        #pragma unroll
        for (int nt = 0; nt < 4; nt++) {
            int col = wn * 64 + nt * 16 + l15;
            wv[nt] = 1.0f / fmaxf(sqrtf(sqs[col][0] + sqs[col][1]), 1e-12f);
        }

        #pragma unroll
        for (int h = 0; h < 2; h++) {
            floatx4 acc[4][2];
            #pragma unroll
            for (int mt = 0; mt < 4; mt++) {
                acc[mt][0] = (floatx4){0.f, 0.f, 0.f, 0.f};
                acc[mt][1] = (floatx4){0.f, 0.f, 0.f, 0.f};
            }
            #pragma unroll
            for (int kk = 0; kk < 4; kk++) {
                short8 bf0 = *(const short8*)(wt + (wn * 64 + (h * 2 + 0) * 16 + l15) * LDX + kk * 32 + q * 8);
                short8 bf1 = *(const short8*)(wt + (wn * 64 + (h * 2 + 1) * 16 + l15) * LDX + kk * 32 + q * 8);
                #pragma unroll
                for (int mt = 0; mt < 4; mt++) {
                    acc[mt][0] = __builtin_amdgcn_mfma_f32_16x16x32_bf16(af[mt][kk], bf0, acc[mt][0], 0, 0, 0);
                    acc[mt][1] = __builtin_amdgcn_mfma_f32_16x16x32_bf16(af[mt][kk], bf1, acc[mt][1], 0, 0, 0);
                }
            }
            #pragma unroll
            for (int mt = 0; mt < 4; mt++)
                #pragma unroll
                for (int n2 = 0; n2 < 2; n2++)
                    #pragma unroll
                    for (int r = 0; r < 4; r++)
                        maxv[mt][h * 2 + n2][r] =
                            fmaxf(maxv[mt][h * 2 + n2][r], acc[mt][n2][r] * wv[h * 2 + n2]);
        }
    }

    #pragma unroll
    for (int mt = 0; mt < 4; mt++) {
        #pragma unroll
        for (int rr = 0; rr < 4; rr++) {
            int row = r0 + wm * 64 + mt * 16 + q * 4 + rr;
            float xi = xinv[row];
            int lb = label[row];
            float m = -1e30f, s = 0.f;
            #pragma unroll
            for (int nt = 0; nt < 4; nt++) {
                int o = o0 + wn * 64 + nt * 16 + l15;
                if (o < NOUT) {
                    float c = maxv[mt][nt][rr] * xi;
                    if (o == lb) {
                        cosl[row] = c;
                    } else {
                        float l = 64.0f * fminf(fmaxf(c, -1.0f + 1e-6f), 1.0f - 1e-6f);
                        s += __expf(l - 64.0f);
                        m = fmaxf(m, l);
                    }
                }
            }
            #pragma unroll
            for (int off = 1; off <= 8; off <<= 1) {
                s += __shfl_xor(s, off);
                m = fmaxf(m, __shfl_xor(m, off));
            }
            if (l15 == 0) {
                partial[(size_t)row * NPART + jb * 4 + wn * 2 + 0] = make_float2(m, s);
                partial[(size_t)row * NPART + jb * 4 + wn * 2 + 1] = make_float2(-1e30f, 0.f);
            }
        }
    }
}

// ---------------------------------------------------------------------------
// Kernel C1: per-row combine (fixed-ref: plain sum+max) + margin.
__global__ void finalize_rows(const float2* __restrict__ partial, const float* __restrict__ cosl,
                              const float* __restrict__ fa, const float* __restrict__ thr,
                              float2* __restrict__ rowres) {
    int w = threadIdx.x >> 6;
    int lane = threadIdx.x & 63;
    int b = blockIdx.x * 4 + w;
    float m = -1e30f, s = 0.0f;
    for (int j = lane; j < NPART; j += 64) {
        float2 p = partial[(size_t)b * NPART + j];
        s += p.y;
        m = fmaxf(m, p.x);
    }
    #pragma unroll
    for (int off = 1; off < 64; off <<= 1) {
        s += __shfl_xor(s, off);
        m = fmaxf(m, __shfl_xor(m, off));
    }
    if (lane == 0) {
        float c = fminf(fmaxf(cosl[b], -1.0f + 1e-6f), 1.0f - 1e-6f);
        float theta = acosf(c);
        float ll = (theta > thr[b]) ? 64.0f * c : 64.0f * cosf(theta + fa[b]);
        float S = s + __expf(ll - 64.0f);
        float loss = 64.0f + logf(S) - ll;
        rowres[b] = make_float2(loss, (ll > m) ? 100.0f : 0.0f);
    }
}

// Kernel C2: deterministic tree reduce of 1024 rows -> 2 scalars.
__global__ void finalize_sum(const float2* __restrict__ rowres, float* __restrict__ out) {
    __shared__ float sl[1024];
    __shared__ float sc[1024];
    int b = threadIdx.x;
    float2 v = rowres[b];
    sl[b] = v.x;
    sc[b] = v.y;
    __syncthreads();
    for (int st = 512; st > 0; st >>= 1) {
        if (b < st) { sl[b] += sl[b + st]; sc[b] += sc[b + st]; }
        __syncthreads();
    }
    if (b == 0) {
        out[0] = sl[0] * (1.0f / 1024.0f);
        out[1] = sc[0] * (1.0f / 1024.0f);
    }
}

// ---------------------------------------------------------------------------
extern "C" void kernel_launch(void* const* d_in, const int* in_sizes, int n_in,
                              void* d_out, int out_size, void* d_ws, size_t ws_size,
                              hipStream_t stream) {
    const float* X      = (const float*)d_in[0];
    const float* factor = (const float*)d_in[1];
    const int*   label  = (const int*)d_in[2];
    const float* W      = (const float*)d_in[3];
    float* out = (float*)d_out;
    float* ws  = (float*)d_ws;

    float*  xinv = ws;                        // 1024
    float*  fa   = ws + 1024;                 // 1024
    float*  thr  = ws + 2048;                 // 1024
    float*  cosl = ws + 3072;                 // 1024
    float2* rowres = (float2*)(ws + 4096);    // 1024 float2
    float2* partial = (float2*)(ws + 6144);   // 1024 x NPART float2 (~2.6 MB)
    unsigned char* Wbf = (unsigned char*)d_ws + 4 * 1024 * 1024;  // 41.4 MB

    const size_t wbf_bytes = (size_t)NK * NCB * 16384;
    const size_t need = 4ull * 1024 * 1024 + wbf_bytes;

    if (ws_size >= need) {
        wconv<<<NK * NCB + 16, 256, 0, stream>>>(W, Wbf, X, factor, xinv, fa, thr);
        gemm_mx<<<1280, 512, 0, stream>>>(X, Wbf, label, xinv, partial, cosl);
    } else {
        rowprep<<<BB, 64, 0, stream>>>(X, factor, xinv, fa, thr);
        gemm_stats<<<640, 256, 0, stream>>>(X, W, label, xinv, partial, cosl);
    }
    finalize_rows<<<BB / 4, 256, 0, stream>>>(partial, cosl, fa, thr, rowres);
    finalize_sum<<<1, BB, 0, stream>>>(rowres, out);
}

// Round 13
// 206.541 us; speedup vs baseline: 1.2677x; 1.0177x over previous
//
#include <hip/hip_runtime.h>
#include <hip/hip_bf16.h>
#include <math.h>

#define BB    1024
#define FIN   128
#define NOUT  10000
#define NBLK  79          // 128-col strips (fallback path)
#define NCB   158         // 64-col regions (Wbf layout)
#define NK    16
#define NPART (NCB * 2)   // per (cb, wn) partials = 316 (both paths)
#define LDX   136         // LDS stride (shorts) for the X tile

typedef __attribute__((ext_vector_type(8))) short short8;
typedef __attribute__((ext_vector_type(4))) float floatx4;

__device__ __forceinline__ unsigned packbf(float a, float b) {
    __hip_bfloat162 h = __float22bfloat162_rn(make_float2(a, b));
    union { __hip_bfloat162 h2; unsigned u; } v;
    v.h2 = h;
    return v.u;
}

// unpack bf16 pair, scale, repack
__device__ __forceinline__ unsigned scale2(unsigned p, float wi) {
    float lo = __uint_as_float(p << 16) * wi;
    float hi = __uint_as_float(p & 0xffff0000u) * wi;
    return packbf(lo, hi);
}

// async global->LDS, 16B per lane; LDS dest = wave-uniform base + lane*16.
__device__ __forceinline__ void async16(const void* g, void* l) {
    __builtin_amdgcn_global_load_lds(
        (const __attribute__((address_space(1))) unsigned int*)g,
        (__attribute__((address_space(3))) unsigned int*)l, 16, 0, 0);
}

// ---------------------------------------------------------------------------
// Kernel A (fallback path only)
__global__ void rowprep(const float* __restrict__ X, const float* __restrict__ factor,
                        float* __restrict__ xinv, float* __restrict__ fa_out,
                        float* __restrict__ thr_out) {
    int b = blockIdx.x;
    int lane = threadIdx.x;
    float v0 = X[b * FIN + lane];
    float v1 = X[b * FIN + 64 + lane];
    float s = v0 * v0 + v1 * v1;
    #pragma unroll
    for (int off = 32; off > 0; off >>= 1) s += __shfl_down(s, off);
    if (lane == 0) {
        xinv[b] = 1.0f / fmaxf(sqrtf(s), 1e-12f);
        float fa = powf(1.5f, factor[b] * (1.0f / 12.0f)) * 0.5f;
        fa_out[b] = fa;
        thr_out[b] = (float)M_PI - fa;
    }
}

// ---------------------------------------------------------------------------
// Kernel W v3 (under test this round): f-half staging (16 KB) + deferred winv
// scale at copy-out. LDS ~33.5 KB -> 4 blocks/CU. Wbf layout unchanged:
// per (k, cb64) 16 KB region [wn(2)][n2(2)][kk(4)][lane=q*16+l15][16B],
// holding bf16(W * winv), o = cb*64 + wn*32 + n2*16 + l15, f=(kk*4+q)*8..+7.
__global__ __launch_bounds__(256) void wconv(
    const float* __restrict__ W, unsigned char* __restrict__ Wbf,
    const float* __restrict__ X, const float* __restrict__ factor,
    float* __restrict__ xinv, float* __restrict__ fa_out, float* __restrict__ thr_out) {

    __shared__ float s[64 * 64];    // 16 KB: one f-half, [f][c] fp32
    __shared__ uint4 wout[1024];    // 16 KB packed (unscaled bf16)
    __shared__ float sq2[256];
    __shared__ float wis[64];

    const int tid = threadIdx.x;

    // rowprep tail blocks
    if (blockIdx.x >= NK * NCB) {
        int rb = blockIdx.x - NK * NCB;   // 0..15
        int w4 = tid >> 6, lane = tid & 63;
        for (int i = w4; i < 64; i += 4) {
            int row = rb * 64 + i;
            float v0 = X[row * FIN + lane];
            float v1 = X[row * FIN + 64 + lane];
            float ss = v0 * v0 + v1 * v1;
            #pragma unroll
            for (int off = 32; off > 0; off >>= 1) ss += __shfl_down(ss, off);
            if (lane == 0) {
                xinv[row] = 1.0f / fmaxf(sqrtf(ss), 1e-12f);
                float fa = powf(1.5f, factor[row] * (1.0f / 12.0f)) * 0.5f;
                fa_out[row] = fa;
                thr_out[row] = (float)M_PI - fa;
            }
        }
        return;
    }

    const int k  = blockIdx.x / NCB;
    const int cb = blockIdx.x - k * NCB;
    const int o0 = cb * 64;
    const int col = tid & 63, seg = tid >> 6;
    const int c   = tid >> 2, sub = tid & 3;
    const int wn_ = c >> 5, n2_ = (c >> 4) & 1, l15_ = c & 15;

    float sqacc = 0.0f;
    #pragma unroll
    for (int h = 0; h < 2; h++) {
        // stage f-half h: 64 rows x 64 cols fp32, coalesced
        #pragma unroll
        for (int it = 0; it < 4; it++) {
            int idx = it * 256 + tid;      // float4 idx 0..1023
            int f = idx >> 4, c4 = idx & 15;
            int o = o0 + c4 * 4;
            float4 v = make_float4(0.f, 0.f, 0.f, 0.f);
            if (o < NOUT)
                v = *(const float4*)(W + (size_t)(k * FIN + h * 64 + f) * NOUT + o);
            *(float4*)(s + f * 64 + c4 * 4) = v;
        }
        __syncthreads();
        // partial sumsq (16 f per thread)
        float ss = 0.0f;
        #pragma unroll
        for (int f2 = 0; f2 < 16; f2++) {
            float x = s[(seg * 16 + f2) * 64 + col];
            ss = fmaf(x, x, ss);
        }
        sqacc += ss;
        // pack this half UNSCALED
        #pragma unroll
        for (int i = 0; i < 2; i++) {
            int tcl = sub * 2 + i;          // 0..7
            int tcg = h * 8 + tcl;          // 0..15
            int kk = tcg >> 2, qq = tcg & 3;
            int fb = tcl * 8;               // LDS f-row base
            uint4 u;
            u.x = packbf(s[(fb + 0) * 64 + c], s[(fb + 1) * 64 + c]);
            u.y = packbf(s[(fb + 2) * 64 + c], s[(fb + 3) * 64 + c]);
            u.z = packbf(s[(fb + 4) * 64 + c], s[(fb + 5) * 64 + c]);
            u.w = packbf(s[(fb + 6) * 64 + c], s[(fb + 7) * 64 + c]);
            wout[wn_ * 512 + n2_ * 256 + kk * 64 + qq * 16 + l15_] = u;
        }
        __syncthreads();   // pack reads done before restage / before copy-out
    }
    sq2[tid] = sqacc;
    __syncthreads();
    if (tid < 64)
        wis[tid] = 1.0f / fmaxf(sqrtf(sq2[tid] + sq2[tid + 64] + sq2[tid + 128] + sq2[tid + 192]), 1e-12f);
    __syncthreads();

    // scaled coalesced copy-out
    unsigned char* dst = Wbf + ((size_t)k * NCB + cb) * 16384;
    #pragma unroll
    for (int i = 0; i < 4; i++) {
        int idx = i * 256 + tid;
        int ccol = ((idx >> 9) << 5) + (((idx >> 8) & 1) << 4) + (idx & 15);
        float wi = wis[ccol];
        uint4 u = wout[idx];
        uint4 r;
        r.x = scale2(u.x, wi);
        r.y = scale2(u.y, wi);
        r.z = scale2(u.z, wi);
        r.w = scale2(u.w, wi);
        *(uint4*)(dst + (size_t)idx * 16) = r;
    }
}

// ---------------------------------------------------------------------------
// Kernel B: PROVEN r11 GEMM restored verbatim. 512 threads = 8 waves
// (4m x 2n of 32x32 wave tiles), block tile 128x64, B staged once per k via
// async16 into 2x16KB LDS dbuf; fixed-reference softmax partials.
__global__ __launch_bounds__(512, 2) void gemm_mx(
    const float* __restrict__ X, const unsigned char* __restrict__ Wbf,
    const int* __restrict__ label, const float* __restrict__ xinv,
    float2* __restrict__ partial, float* __restrict__ cosl) {

    __shared__ union {
        short xs[128 * LDX];   // 34816 B, X staging
        short bb[2][8192];     // 2 x 16 KB B buffers
    } u;

    const int tid  = threadIdx.x;
    const int lane = tid & 63;
    const int w    = tid >> 6;     // 0..7
    const int l15  = lane & 15;
    const int q    = lane >> 4;
    const int wm   = w & 3;        // 4 m-slots (32 rows each)
    const int wn   = w >> 2;       // 2 n-slots (32 cols each)

    // XCD-aware decode: ids {group*64 + y*8 + xcd} -> cb = group*8 + xcd
    const int id    = blockIdx.x;
    const int group = id >> 6;
    const int sub   = id & 63;
    const int cb    = group * 8 + (sub & 7);
    const int y     = sub >> 3;            // 0..7
    if (cb >= NCB) return;
    const int r0 = y * 128;
    const int o0 = cb * 64;

    // ---- stage X tile (128 rows) as bf16 with xinv folded ----
    #pragma unroll
    for (int it = 0; it < 8; it++) {
        int idx = it * 512 + tid;      // float4 index 0..4095
        int row = idx >> 5;
        int c4  = idx & 31;
        const float4 v = *(const float4*)(X + (size_t)(r0 + row) * FIN + c4 * 4);
        float xi = xinv[r0 + row];
        uint2 p;
        p.x = packbf(v.x * xi, v.y * xi);
        p.y = packbf(v.z * xi, v.w * xi);
        *(uint2*)(u.xs + row * LDX + c4 * 4) = p;
    }
    __syncthreads();

    short8 af[2][4];
    #pragma unroll
    for (int mt = 0; mt < 2; mt++)
        #pragma unroll
        for (int kk = 0; kk < 4; kk++)
            af[mt][kk] = *(const short8*)(u.xs + (wm * 32 + mt * 16 + l15) * LDX + kk * 32 + q * 8);
    __syncthreads();   // X area now reusable as B buffers

    // per-step B staging: 16 KB; wave w loads 2 KB (2 async16 calls)
    auto issue = [&](int k) {
        const unsigned char* g = Wbf + ((size_t)k * NCB + cb) * 16384
                                 + (size_t)w * 2048 + (size_t)lane * 16;
        short* d = u.bb[k & 1] + w * 1024;
        async16(g, d);
        async16(g + 1024, d + 512);
    };

    issue(0);

    floatx4 maxv[2][2];
    #pragma unroll
    for (int mt = 0; mt < 2; mt++)
        #pragma unroll
        for (int n2 = 0; n2 < 2; n2++)
            #pragma unroll
            for (int r = 0; r < 4; r++)
                maxv[mt][n2][r] = -INFINITY;

    for (int k = 0; k < NK; k++) {
        __syncthreads();   // loads(k) landed; prior buffer reads done
        if (k < NK - 1) issue(k + 1);
        const short* wt = u.bb[k & 1];

        floatx4 acc[2][2];
        #pragma unroll
        for (int mt = 0; mt < 2; mt++)
            #pragma unroll
            for (int n2 = 0; n2 < 2; n2++)
                acc[mt][n2] = (floatx4){0.f, 0.f, 0.f, 0.f};
        #pragma unroll
        for (int kk = 0; kk < 4; kk++) {
            short8 bf[2];
            #pragma unroll
            for (int n2 = 0; n2 < 2; n2++)
                bf[n2] = *(const short8*)(wt + wn * 4096 + n2 * 2048 + kk * 512 + lane * 8);
            #pragma unroll
            for (int mt = 0; mt < 2; mt++)
                #pragma unroll
                for (int n2 = 0; n2 < 2; n2++)
                    acc[mt][n2] = __builtin_amdgcn_mfma_f32_16x16x32_bf16(
                        af[mt][kk], bf[n2], acc[mt][n2], 0, 0, 0);
        }
        #pragma unroll
        for (int mt = 0; mt < 2; mt++)
            #pragma unroll
            for (int n2 = 0; n2 < 2; n2++)
                #pragma unroll
                for (int r = 0; r < 4; r++)
                    maxv[mt][n2][r] = fmaxf(maxv[mt][n2][r], acc[mt][n2][r]);
    }

    // ---- epilogue: fixed-reference partial softmax (label col excluded) ----
    #pragma unroll
    for (int mt = 0; mt < 2; mt++) {
        #pragma unroll
        for (int rr = 0; rr < 4; rr++) {
            int row = r0 + wm * 32 + mt * 16 + q * 4 + rr;
            int lb = label[row];
            float m = -1e30f, sum = 0.f;
            #pragma unroll
            for (int n2 = 0; n2 < 2; n2++) {
                int o = o0 + wn * 32 + n2 * 16 + l15;
                if (o < NOUT) {
                    float cc = maxv[mt][n2][rr];
                    if (o == lb) {
                        cosl[row] = cc;   // unique writer grid-wide
                    } else {
                        float l = 64.0f * fminf(fmaxf(cc, -1.0f + 1e-6f), 1.0f - 1e-6f);
                        sum += __expf(l - 64.0f);
                        m = fmaxf(m, l);
                    }
                }
            }
            #pragma unroll
            for (int off = 1; off <= 8; off <<= 1) {
                sum += __shfl_xor(sum, off);
                m = fmaxf(m, __shfl_xor(m, off));
            }
            if (l15 == 0)
                partial[(size_t)row * NPART + cb * 2 + wn] = make_float2(m, sum);
        }
    }
}

// ---------------------------------------------------------------------------
// Fallback GEMM (used when ws_size can't hold Wbf). Stride NPART partials.
__global__ __launch_bounds__(256, 2) void gemm_stats(
    const float* __restrict__ X, const float* __restrict__ W,
    const int* __restrict__ label, const float* __restrict__ xinv,
    float2* __restrict__ partial, float* __restrict__ cosl) {

    __shared__ short xs[128 * LDX];
    __shared__ short wt[128 * LDX];
    __shared__ float sqs[128][2];

    const int tid  = threadIdx.x;
    const int lane = tid & 63;
    const int w    = tid >> 6;
    const int l15  = lane & 15;
    const int q    = lane >> 4;
    const int wm   = w & 1;
    const int wn   = w >> 1;

    const int id    = blockIdx.x;
    const int group = id >> 6;
    const int sub   = id & 63;
    const int jb    = group * 8 + (sub & 7);
    const int y     = sub >> 3;
    if (jb >= NBLK) return;
    const int r0 = y * 128;
    const int o0 = jb * 128;

    #pragma unroll
    for (int it = 0; it < 16; it++) {
        int idx = it * 256 + tid;
        int row = idx >> 5;
        int c4  = idx & 31;
        const float4 v = *(const float4*)(X + (size_t)(r0 + row) * FIN + c4 * 4);
        uint2 p;
        p.x = packbf(v.x, v.y);
        p.y = packbf(v.z, v.w);
        *(uint2*)(xs + row * LDX + c4 * 4) = p;
    }

    const int st_o = (w & 1) * 64 + lane;
    const int st_f = (w >> 1) * 64;
    const int st_h = w >> 1;
    const int go   = o0 + st_o;
    const bool ov  = go < NOUT;

    float rw[64];
    {
        const float* Wp = W + (size_t)st_f * NOUT + go;
        #pragma unroll
        for (int g = 0; g < 16; g++)
            #pragma unroll
            for (int cc = 0; cc < 4; cc++)
                rw[g * 4 + cc] = ov ? Wp[(size_t)(g * 4 + cc) * NOUT] : 0.0f;
    }
    __syncthreads();

    short8 af[4][4];
    #pragma unroll
    for (int mt = 0; mt < 4; mt++)
        #pragma unroll
        for (int kk = 0; kk < 4; kk++)
            af[mt][kk] = *(const short8*)(xs + (wm * 64 + mt * 16 + l15) * LDX + kk * 32 + q * 8);

    floatx4 maxv[4][4];
    #pragma unroll
    for (int mt = 0; mt < 4; mt++)
        #pragma unroll
        for (int nt = 0; nt < 4; nt++)
            #pragma unroll
            for (int r = 0; r < 4; r++)
                maxv[mt][nt][r] = -INFINITY;

    for (int k = 0; k < NK; k++) {
        float sq = 0.0f;
        uint2 pk[16];
        #pragma unroll
        for (int g = 0; g < 16; g++) {
            float a0 = rw[g * 4 + 0], a1 = rw[g * 4 + 1];
            float a2 = rw[g * 4 + 2], a3 = rw[g * 4 + 3];
            sq = fmaf(a0, a0, sq); sq = fmaf(a1, a1, sq);
            sq = fmaf(a2, a2, sq); sq = fmaf(a3, a3, sq);
            pk[g].x = packbf(a0, a1);
            pk[g].y = packbf(a2, a3);
        }
        __syncthreads();
        #pragma unroll
        for (int g = 0; g < 16; g++)
            *(uint2*)(wt + st_o * LDX + st_f + g * 4) = pk[g];
        sqs[st_o][st_h] = sq;
        __syncthreads();

        if (k < NK - 1) {
            const float* Wn = W + ((size_t)(k + 1) * FIN + st_f) * NOUT + go;
            #pragma unroll
            for (int g = 0; g < 16; g++)
                #pragma unroll
                for (int cc = 0; cc < 4; cc++)
                    rw[g * 4 + cc] = ov ? Wn[(size_t)(g * 4 + cc) * NOUT] : 0.0f;
        }

        float wv[4];
        #pragma unroll
        for (int nt = 0; nt < 4; nt++) {
            int colx = wn * 64 + nt * 16 + l15;
            wv[nt] = 1.0f / fmaxf(sqrtf(sqs[colx][0] + sqs[colx][1]), 1e-12f);
        }

        #pragma unroll
        for (int h = 0; h < 2; h++) {
            floatx4 acc[4][2];
            #pragma unroll
            for (int mt = 0; mt < 4; mt++) {
                acc[mt][0] = (floatx4){0.f, 0.f, 0.f, 0.f};
                acc[mt][1] = (floatx4){0.f, 0.f, 0.f, 0.f};
            }
            #pragma unroll
            for (int kk = 0; kk < 4; kk++) {
                short8 bf0 = *(const short8*)(wt + (wn * 64 + (h * 2 + 0) * 16 + l15) * LDX + kk * 32 + q * 8);
                short8 bf1 = *(const short8*)(wt + (wn * 64 + (h * 2 + 1) * 16 + l15) * LDX + kk * 32 + q * 8);
                #pragma unroll
                for (int mt = 0; mt < 4; mt++) {
                    acc[mt][0] = __builtin_amdgcn_mfma_f32_16x16x32_bf16(af[mt][kk], bf0, acc[mt][0], 0, 0, 0);
                    acc[mt][1] = __builtin_amdgcn_mfma_f32_16x16x32_bf16(af[mt][kk], bf1, acc[mt][1], 0, 0, 0);
                }
            }
            #pragma unroll
            for (int mt = 0; mt < 4; mt++)
                #pragma unroll
                for (int n2 = 0; n2 < 2; n2++)
                    #pragma unroll
                    for (int r = 0; r < 4; r++)
                        maxv[mt][h * 2 + n2][r] =
                            fmaxf(maxv[mt][h * 2 + n2][r], acc[mt][n2][r] * wv[h * 2 + n2]);
        }
    }

    #pragma unroll
    for (int mt = 0; mt < 4; mt++) {
        #pragma unroll
        for (int rr = 0; rr < 4; rr++) {
            int row = r0 + wm * 64 + mt * 16 + q * 4 + rr;
            float xi = xinv[row];
            int lb = label[row];
            float m = -1e30f, sum = 0.f;
            #pragma unroll
            for (int nt = 0; nt < 4; nt++) {
                int o = o0 + wn * 64 + nt * 16 + l15;
                if (o < NOUT) {
                    float cc = maxv[mt][nt][rr] * xi;
                    if (o == lb) {
                        cosl[row] = cc;
                    } else {
                        float l = 64.0f * fminf(fmaxf(cc, -1.0f + 1e-6f), 1.0f - 1e-6f);
                        sum += __expf(l - 64.0f);
                        m = fmaxf(m, l);
                    }
                }
            }
            #pragma unroll
            for (int off = 1; off <= 8; off <<= 1) {
                sum += __shfl_xor(sum, off);
                m = fmaxf(m, __shfl_xor(m, off));
            }
            if (l15 == 0) {
                partial[(size_t)row * NPART + jb * 4 + wn * 2 + 0] = make_float2(m, sum);
                partial[(size_t)row * NPART + jb * 4 + wn * 2 + 1] = make_float2(-1e30f, 0.f);
            }
        }
    }
}

// ---------------------------------------------------------------------------
// Kernel C1: per-row combine (fixed-ref: plain sum+max) + margin. np = stride.
__global__ void finalize_rows(const float2* __restrict__ partial, const float* __restrict__ cosl,
                              const float* __restrict__ fa, const float* __restrict__ thr,
                              float2* __restrict__ rowres, int np) {
    int w = threadIdx.x >> 6;
    int lane = threadIdx.x & 63;
    int b = blockIdx.x * 4 + w;
    float m = -1e30f, s = 0.0f;
    for (int j = lane; j < np; j += 64) {
        float2 p = partial[(size_t)b * np + j];
        s += p.y;
        m = fmaxf(m, p.x);
    }
    #pragma unroll
    for (int off = 1; off < 64; off <<= 1) {
        s += __shfl_xor(s, off);
        m = fmaxf(m, __shfl_xor(m, off));
    }
    if (lane == 0) {
        float c = fminf(fmaxf(cosl[b], -1.0f + 1e-6f), 1.0f - 1e-6f);
        float theta = acosf(c);
        float ll = (theta > thr[b]) ? 64.0f * c : 64.0f * cosf(theta + fa[b]);
        float S = s + __expf(ll - 64.0f);
        float loss = 64.0f + logf(S) - ll;
        rowres[b] = make_float2(loss, (ll > m) ? 100.0f : 0.0f);
    }
}

// Kernel C2: deterministic tree reduce of 1024 rows -> 2 scalars.
__global__ void finalize_sum(const float2* __restrict__ rowres, float* __restrict__ out) {
    __shared__ float sl[1024];
    __shared__ float sc[1024];
    int b = threadIdx.x;
    float2 v = rowres[b];
    sl[b] = v.x;
    sc[b] = v.y;
    __syncthreads();
    for (int st = 512; st > 0; st >>= 1) {
        if (b < st) { sl[b] += sl[b + st]; sc[b] += sc[b + st]; }
        __syncthreads();
    }
    if (b == 0) {
        out[0] = sl[0] * (1.0f / 1024.0f);
        out[1] = sc[0] * (1.0f / 1024.0f);
    }
}

// ---------------------------------------------------------------------------
extern "C" void kernel_launch(void* const* d_in, const int* in_sizes, int n_in,
                              void* d_out, int out_size, void* d_ws, size_t ws_size,
                              hipStream_t stream) {
    const float* X      = (const float*)d_in[0];
    const float* factor = (const float*)d_in[1];
    const int*   label  = (const int*)d_in[2];
    const float* W      = (const float*)d_in[3];
    float* out = (float*)d_out;
    float* ws  = (float*)d_ws;

    float*  xinv = ws;                        // 1024
    float*  fa   = ws + 1024;                 // 1024
    float*  thr  = ws + 2048;                 // 1024
    float*  cosl = ws + 3072;                 // 1024
    float2* rowres = (float2*)(ws + 4096);    // 1024 float2
    float2* partial = (float2*)(ws + 6144);   // 1024 x 316 float2 (~2.6 MB)
    unsigned char* Wbf = (unsigned char*)d_ws + 4 * 1024 * 1024;  // 41.4 MB

    const size_t wbf_bytes = (size_t)NK * NCB * 16384;
    const size_t need = 4ull * 1024 * 1024 + wbf_bytes;

    if (ws_size >= need) {
        wconv<<<NK * NCB + 16, 256, 0, stream>>>(W, Wbf, X, factor, xinv, fa, thr);
        gemm_mx<<<1280, 512, 0, stream>>>(X, Wbf, label, xinv, partial, cosl);
    } else {
        rowprep<<<BB, 64, 0, stream>>>(X, factor, xinv, fa, thr);
        gemm_stats<<<640, 256, 0, stream>>>(X, W, label, xinv, partial, cosl);
    }
    finalize_rows<<<BB / 4, 256, 0, stream>>>(partial, cosl, fa, thr, rowres, NPART);
    finalize_sum<<<1, BB, 0, stream>>>(rowres, out);
}